// Round 10
// baseline (354.353 us; speedup 1.0000x reference)
//
#include <hip/hip_runtime.h>
#include <math.h>

#define LEAKC 0.2f

#define NB 4
#define NC 64
#define LLEN 16384
#define HW 2304
#define PP 54          // padded pitch (48 + 2*3)
#define PHW 2916       // 54*54

typedef __attribute__((ext_vector_type(8))) short short8;
typedef __attribute__((ext_vector_type(4))) float floatx4;

__device__ __forceinline__ float leaky(float x){ return x > 0.f ? x : LEAKC*x; }

__device__ __forceinline__ float wave_sum64(float v){
  for(int off=32;off;off>>=1) v += __shfl_xor(v,off);
  return v;
}

__device__ __forceinline__ unsigned short f2bf(float x){
  unsigned u=__float_as_uint(x);
  unsigned r=u+0x7FFFu+((u>>16)&1u);
  return (unsigned short)(r>>16);
}

__device__ __forceinline__ void threefry2x32(unsigned k0, unsigned k1, unsigned& x0, unsigned& x1){
  unsigned ks0=k0, ks1=k1, ks2=k0^k1^0x1BD11BDAu;
  x0+=ks0; x1+=ks1;
  const int rot0[4]={13,15,26,6};
  const int rot1[4]={17,29,16,24};
#define TF_APPLY(rr) {for(int r=0;r<4;r++){x0+=x1; x1=(x1<<rr[r])|(x1>>(32-rr[r])); x1^=x0;}}
  TF_APPLY(rot0); x0+=ks1; x1+=ks2+1u;
  TF_APPLY(rot1); x0+=ks2; x1+=ks0+2u;
  TF_APPLY(rot0); x0+=ks0; x1+=ks1+3u;
  TF_APPLY(rot1); x0+=ks1; x1+=ks2+4u;
  TF_APPLY(rot0); x0+=ks2; x1+=ks0+5u;
#undef TF_APPLY
}

__device__ __forceinline__ float jax_uniform128(int i){
  unsigned x0=0u, x1=(unsigned)i;
  threefry2x32(0u,42u,x0,x1);
  unsigned bits = x0 ^ x1;
  unsigned fb=(bits>>9)|0x3f800000u;
  float f=__uint_as_float(fb)-1.0f;
  float u=f*(1.0f-1e-10f)+1e-10f;
  return fmaxf(1e-10f,u);
}

// ---------------- k_pre: stats (0..255) + padded imgT transpose (256..399) + weight prep (400..867) ----------------
__global__ __launch_bounds__(256) void k_pre(const float* __restrict__ task_f,
                      const float* __restrict__ w1A, const float* __restrict__ w1B,
                      float* __restrict__ totA, float* __restrict__ a0A, float* __restrict__ aLA,
                      float* __restrict__ totB, float* __restrict__ a0B, float* __restrict__ aLB,
                      float* __restrict__ rmsacc,
                      const float* __restrict__ img,
                      const float* __restrict__ w1, const float* __restrict__ w2,
                      const float* __restrict__ wa,
                      unsigned short* __restrict__ imgTP,
                      unsigned short* __restrict__ W1T, unsigned short* __restrict__ W2T,
                      unsigned short* __restrict__ WAT){
  if(blockIdx.x<256){
    int b=blockIdx.x>>6, seg=blockIdx.x&63;
    const float* x=task_f+b*LLEN;
    float tA[4]={0,0,0,0};
    float tB[64];
#pragma unroll
    for(int c=0;c<64;c++) tB[c]=0.f;
    float sq=0.f;
    int l=seg*256+threadIdx.x;
    {
      float xm=(l>0)?x[l-1]:0.f;
      float xc=x[l];
      float xp=(l<LLEN-1)?x[l+1]:0.f;
      sq=xc*xc;
#pragma unroll
      for(int c=0;c<4;c++){
        float a=leaky(w1A[c*3+0]*xm + w1A[c*3+1]*xc + w1A[c*3+2]*xp);
        tA[c]=a;
        if(l==0) a0A[b*4+c]=a;
        if(l==LLEN-1) aLA[b*4+c]=a;
      }
#pragma unroll
      for(int c=0;c<64;c++){
        float a=leaky(w1B[c*3+0]*xm + w1B[c*3+1]*xc + w1B[c*3+2]*xp);
        tB[c]=a;
        if(l==0) a0B[b*64+c]=a;
        if(l==LLEN-1) aLB[b*64+c]=a;
      }
    }
    sq=wave_sum64(sq);
#pragma unroll
    for(int c=0;c<4;c++) tA[c]=wave_sum64(tA[c]);
#pragma unroll
    for(int c=0;c<64;c++){
      float v=tB[c];
      for(int off=32;off;off>>=1) v+=__shfl_down(v,off);
      tB[c]=v;
    }
    __shared__ float redB[4][64];
    __shared__ float redA[4][4];
    __shared__ float redQ[4];
    int wave=threadIdx.x>>6, lane=threadIdx.x&63;
    if(lane==0){
#pragma unroll
      for(int c=0;c<64;c++) redB[wave][c]=tB[c];
#pragma unroll
      for(int c=0;c<4;c++) redA[wave][c]=tA[c];
      redQ[wave]=sq;
    }
    __syncthreads();
    if(threadIdx.x<64){
      float s=redB[0][threadIdx.x]+redB[1][threadIdx.x]+redB[2][threadIdx.x]+redB[3][threadIdx.x];
      atomicAdd(&totB[b*64+threadIdx.x], s);
    } else if(threadIdx.x<68){
      int c=threadIdx.x-64;
      float s=redA[0][c]+redA[1][c]+redA[2][c]+redA[3][c];
      atomicAdd(&totA[b*4+c], s);
    } else if(threadIdx.x==68){
      atomicAdd(&rmsacc[b], redQ[0]+redQ[1]+redQ[2]+redQ[3]);
    }
  } else if(blockIdx.x<400){
    int blk=blockIdx.x-256;
    int b=blk/36, t=blk%36;
    int p0=t*64;
    __shared__ float tile[64][65];
    int pp=threadIdx.x&63, c4=threadIdx.x>>6;
    for(int r=0;r<16;r++){
      int c=c4*16+r;
      tile[c][pp]=img[(b*64+c)*HW + p0+pp];
    }
    __syncthreads();
    int pxl=threadIdx.x>>2, cg=(threadIdx.x&3)*16;
    unsigned out[8];
#pragma unroll
    for(int q=0;q<8;q++){
      unsigned lo=f2bf(tile[cg+2*q][pxl]);
      unsigned hi=f2bf(tile[cg+2*q+1][pxl]);
      out[q]=lo|(hi<<16);
    }
    int px=p0+pxl;
    int h=px/48, w=px-h*48;
    int poff=(h+3)*PP+(w+3);
    unsigned* dst=(unsigned*)(imgTP + ((size_t)(b*PHW+poff))*64 + cg);
#pragma unroll
    for(int q=0;q<8;q++) dst[q]=out[q];
  } else {
    int n=(blockIdx.x-400)*256+threadIdx.x;
    if(n<9*64*64){
      int tap=n>>12, oc=(n>>6)&63, c=n&63;
      W1T[n]=f2bf(w1[oc*576+c*9+tap]);
    } else if(n<9*64*64+9*128*64){
      int m=n-9*64*64;
      int tap=m/8192, r=m-tap*8192, oc=r>>6, c=r&63;
      W2T[m]=f2bf(w2[oc*576+c*9+tap]);
    } else {
      int q=n-9*64*64-9*128*64;
      if(q<9*16*64){
        int tap=q>>10, r=q&1023, o=r>>6, c=r&63;
        WAT[q]=(o<8)?f2bf(wa[o*576+c*9+tap]):(unsigned short)0;
      }
    }
  }
}

// ---------------- k_conv1: ic1 MFMA one-row/block (0..191) + iA MFMA mean (192..215) ----------------
__global__ __launch_bounds__(256) void k_conv1(const unsigned short* __restrict__ imgTP,
                        const unsigned short* __restrict__ W1T,
                        const unsigned short* __restrict__ WAT,
                        const float* __restrict__ bn1, const float* __restrict__ bnA,
                        unsigned short* __restrict__ ie1TP, float* __restrict__ i1){
  int lane=threadIdx.x&63, mt=threadIdx.x>>6;
  int n0=lane&15, kg=lane>>4;
  if(blockIdx.x<192){
    int blk=blockIdx.x;
    int b=blk/48, r0=blk-b*48;
    const unsigned short* ib=imgTP+(size_t)b*PHW*64;
    floatx4 acc[3];
#pragma unroll
    for(int i=0;i<3;i++) acc[i]=(floatx4){0.f,0.f,0.f,0.f};
#pragma unroll
    for(int ti=0;ti<3;ti++){
      int r=r0+ti-1+3;
#pragma unroll
      for(int tj=0;tj<3;tj++){
        int tap=ti*3+tj;
        const unsigned short* Ab=W1T+(size_t)tap*4096;
#pragma unroll
        for(int c0=0;c0<64;c0+=32){
          short8 a=*(const short8*)(Ab+((mt*16+n0)*64+c0+kg*8));
#pragma unroll
          for(int wc=0;wc<3;wc++){
            int w=wc*16+n0+tj-1+3;
            short8 bv=*(const short8*)(ib+((size_t)(r*PP+w)*64+c0+kg*8));
            acc[wc]=__builtin_amdgcn_mfma_f32_16x16x32_bf16(a,bv,acc[wc],0,0,0);
          }
        }
      }
    }
    int obase=mt*16+kg*4;
    float scale[4],m_[4],be_[4];
#pragma unroll
    for(int reg=0;reg<4;reg++){
      int o=obase+reg;
      scale[reg]=bn1[o]/sqrtf(bn1[192+o]+1e-5f);
      m_[reg]=bn1[128+o]; be_[reg]=bn1[64+o];
    }
#pragma unroll
    for(int wc=0;wc<3;wc++){
      int poff=(r0+3)*PP + wc*16+n0+3;
      float v0=leaky((acc[wc][0]-m_[0])*scale[0]+be_[0]);
      float v1=leaky((acc[wc][1]-m_[1])*scale[1]+be_[1]);
      float v2=leaky((acc[wc][2]-m_[2])*scale[2]+be_[2]);
      float v3=leaky((acc[wc][3]-m_[3])*scale[3]+be_[3]);
      unsigned w0=f2bf(v0)|((unsigned)f2bf(v1)<<16);
      unsigned w1=f2bf(v2)|((unsigned)f2bf(v3)<<16);
      uint2 pk={w0,w1};
      *(uint2*)(ie1TP+((size_t)(b*PHW+poff)*64+obase))=pk;
    }
  } else {
    int blk=blockIdx.x-192;
    int b=blk/6, hg=blk%6;
    int hp=hg*4+mt;
    int h0=hp*2;
    const unsigned short* ib=imgTP+(size_t)b*PHW*64;
    floatx4 acc[6];
#pragma unroll
    for(int i=0;i<6;i++) acc[i]=(floatx4){0.f,0.f,0.f,0.f};
#pragma unroll
    for(int ti=0;ti<3;ti++){
#pragma unroll
      for(int tj=0;tj<3;tj++){
        int tap=ti*3+tj;
        const unsigned short* Ab=WAT+(size_t)tap*1024;
#pragma unroll
        for(int c0=0;c0<64;c0+=32){
          short8 a=*(const short8*)(Ab+(n0*64+c0+kg*8));
#pragma unroll
          for(int rr=0;rr<2;rr++){
            int r=h0+rr+ti-1+3;
#pragma unroll
            for(int wc=0;wc<3;wc++){
              int w=wc*16+n0+tj-1+3;
              short8 bv=*(const short8*)(ib+((size_t)(r*PP+w)*64+c0+kg*8));
              acc[rr*3+wc]=__builtin_amdgcn_mfma_f32_16x16x32_bf16(a,bv,acc[rr*3+wc],0,0,0);
            }
          }
        }
      }
    }
    int obase=kg*4;
#pragma unroll
    for(int reg=0;reg<4;reg++){
      int o=obase+reg;
      float part=0;
      if(o<8){
        float scale=bnA[o]/sqrtf(bnA[24+o]+1e-5f);
        float m_=bnA[16+o], be_=bnA[8+o];
#pragma unroll
        for(int i=0;i<6;i++) part+=leaky((acc[i][reg]-m_)*scale+be_);
      }
      for(int off=1;off<16;off<<=1) part+=__shfl_xor(part,off);
      if(n0==0 && o<8) atomicAdd(&i1[b*8+o], part*(1.f/2304.f));
    }
  }
}

// ---------------- bv_ic2 conv via MFMA + mean; tap-row split via blockIdx.z ----------------
__global__ __launch_bounds__(256) void k_ic2M(const unsigned short* __restrict__ ie1TP,
                       const unsigned short* __restrict__ W2T,
                       const float* __restrict__ bn, float* __restrict__ ie){
  int blk=blockIdx.x;
  int b=blk/24, hp=blk-b*24;
  int mo=blockIdx.y*64;
  int ti=blockIdx.z;
  int lane=threadIdx.x&63, mt=threadIdx.x>>6;
  int n0=lane&15, kg=lane>>4;
  int h0=hp*2;
  const unsigned short* ib=ie1TP+(size_t)b*PHW*64;
  floatx4 acc[6];
#pragma unroll
  for(int i=0;i<6;i++) acc[i]=(floatx4){0.f,0.f,0.f,0.f};
#pragma unroll
  for(int tj=0;tj<3;tj++){
    int tap=ti*3+tj;
    const unsigned short* Ab=W2T+(size_t)tap*8192;
#pragma unroll
    for(int c0=0;c0<64;c0+=32){
      short8 a=*(const short8*)(Ab+((mo+mt*16+n0)*64+c0+kg*8));
#pragma unroll
      for(int rr=0;rr<2;rr++){
        int r=h0+rr+ti-1+3;
#pragma unroll
        for(int wc=0;wc<3;wc++){
          int w=wc*16+n0+tj-1+3;
          short8 bv=*(const short8*)(ib+((size_t)(r*PP+w)*64+c0+kg*8));
          acc[rr*3+wc]=__builtin_amdgcn_mfma_f32_16x16x32_bf16(a,bv,acc[rr*3+wc],0,0,0);
        }
      }
    }
  }
  // partial conv sums for this tap-row; bn affine is linear so apply (acc-m*)??  NO:
  // leaky is NOT linear — must apply bn+leaky only on the FULL conv sum.
  // So tap-split must accumulate raw conv partials in global, then a tiny pass applies bn+leaky+mean.
  // Instead: accumulate raw partial into xpart via atomicAdd, second kernel does bn+leaky+mean.
  int obase=mo+mt*16+kg*4;
#pragma unroll
  for(int reg=0;reg<4;reg++){
    int o=obase+reg;
#pragma unroll
    for(int rr=0;rr<2;rr++){
#pragma unroll
      for(int wc=0;wc<3;wc++){
        int px=(h0+rr)*48+wc*16+n0;
        atomicAdd(&ie[((size_t)b*128+o)*HW+px], acc[rr*3+wc][reg]);
      }
    }
  }
}

// ---------------- ic2 post: bn + leaky + spatial mean over the accumulated conv ----------------
__global__ __launch_bounds__(256) void k_ic2post(const float* __restrict__ xpart, const float* __restrict__ bn,
                          float* __restrict__ ie){
  int b=blockIdx.x>>7, o=blockIdx.x&127;
  float scale=bn[o]/sqrtf(bn[384+o]+1e-5f);
  float m_=bn[256+o], be_=bn[128+o];
  const float* xp=xpart+((size_t)b*128+o)*HW;
  float s=0;
  for(int p=threadIdx.x;p<HW;p+=256) s+=leaky((xp[p]-m_)*scale+be_);
  s=wave_sum64(s);
  __shared__ float red[4];
  int wave=threadIdx.x>>6, lane=threadIdx.x&63;
  if(lane==0) red[wave]=s;
  __syncthreads();
  if(threadIdx.x==0) ie[b*128+o]=(red[0]+red[1]+red[2]+red[3])*(1.f/2304.f);
}

// ---------------- fused mid, PER-BATCH block (grid=4) ----------------
__global__ __launch_bounds__(256) void k_mid(
    const float* __restrict__ totA, const float* __restrict__ a0A, const float* __restrict__ aLA,
    const float* __restrict__ totB, const float* __restrict__ a0B, const float* __restrict__ aLB,
    const float* __restrict__ rmsacc,
    const float* __restrict__ tA_w2, const float* __restrict__ bv_t2,
    const float* __restrict__ i1, const float* __restrict__ ie,
    const float* __restrict__ at_w1, const float* __restrict__ at_b1,
    const float* __restrict__ at_ln_g, const float* __restrict__ at_ln_b,
    const float* __restrict__ at_w2, const float* __restrict__ at_b2,
    const float* __restrict__ protos,
    const float* __restrict__ bv_w1, const float* __restrict__ bv_b1,
    const float* __restrict__ bv_ln_g, const float* __restrict__ bv_ln_b,
    const float* __restrict__ bv_w2, const float* __restrict__ bv_b2,
    const float* __restrict__ bank,
    const float* __restrict__ m1_w1, const float* __restrict__ m1_b1,
    const float* __restrict__ m1_g,  const float* __restrict__ m1_bb,
    const float* __restrict__ m3_w1, const float* __restrict__ m3_b1,
    const float* __restrict__ m3_g,  const float* __restrict__ m3_bb,
    int* __restrict__ idxo, float* __restrict__ hid1, float* __restrict__ hid3){
  int b=blockIdx.x;
  int tid=threadIdx.x;
  int lane=tid&63, wv=tid>>6;
  const float invL=1.0f/16384.0f;
  __shared__ float sT[64], s0[64], sL[64];
  __shared__ float te_s[128], t1_s[8];
  __shared__ float f1[16], h[64], tif[128], tifn[128], tden[8], pden[4], pn[64], z[32];
  __shared__ int sidx[8], sfirst[4], srank[8], rows[8];
  __shared__ float fbuf[256], hh[64], ffn_s[256], finv_s;
  __shared__ float scores[64];
  __shared__ int order[64];
  __shared__ float bvf[2048];

  if(tid<64){ sT[tid]=totB[b*64+tid]; s0[tid]=a0B[b*64+tid]; sL[tid]=aLB[b*64+tid]; }
  __syncthreads();
  float scB=1.0f/(sqrtf(rmsacc[b]*invL)+1e-8f);
  if(tid<128){
    int c2=tid;
    const float* wr=bv_t2+c2*192;
    float s=0;
    for(int c1=0;c1<64;c1+=8){
      float4 q[6];
      const float4* r4=(const float4*)(wr+c1*3);
#pragma unroll
      for(int u=0;u<6;u++) q[u]=r4[u];
      const float* qq=(const float*)q;
#pragma unroll
      for(int u=0;u<8;u++){
        int c=c1+u;
        float T=sT[c], A0=s0[c], AL=sL[c];
        s += qq[u*3+0]*(T-AL) + qq[u*3+1]*T + qq[u*3+2]*(T-A0);
      }
    }
    te_s[c2]=s*invL*scB;
  } else if(tid<136){
    int c2=tid-128;
    float s=0;
    for(int c1=0;c1<4;c1++){
      float T=totA[b*4+c1], A0=a0A[b*4+c1], AL=aLA[b*4+c1];
      const float* w=&tA_w2[(c2*4+c1)*3];
      s += w[0]*(T-AL) + w[1]*T + w[2]*(T-A0);
    }
    t1_s[c2]=s*invL;
  }
  __syncthreads();

  if(tid<8) f1[tid]=t1_s[tid];
  else if(tid<16) f1[tid]=i1[b*8+tid-8];
  __syncthreads();
  if(tid<64){
    float s=at_b1[lane];
#pragma unroll
    for(int i=0;i<16;i++) s+=f1[i]*at_w1[i*64+lane];
    float mu=wave_sum64(s)*(1.f/64.f);
    float d=s-mu;
    float var=wave_sum64(d*d)*(1.f/64.f);
    h[lane]=fmaxf(d*(1.0f/sqrtf(var+1e-5f))*at_ln_g[lane]+at_ln_b[lane],0.f);
  }
  __syncthreads();
  if(tid<128){
    int n=tid;
    float a0=0,a1=0;
    for(int k=0;k<64;k+=2){
      a0+=h[k]*at_w2[k*128+n];
      a1+=h[k+1]*at_w2[(k+1)*128+n];
    }
    tif[n]=at_b2[n]+a0+a1;
  }
  __syncthreads();
  if(tid<8){
    int f=tid;
    float ss=0; for(int e=0;e<16;e++){float v=tif[e*8+f]; ss+=v*v;}
    tden[f]=fmaxf(sqrtf(ss),1e-8f);
  } else if(tid<12){
    int t=tid-8;
    float ss=0; for(int e=0;e<16;e++){float v=protos[t*16+e]; ss+=v*v;}
    pden[t]=fmaxf(sqrtf(ss),1e-8f);
  }
  __syncthreads();
  if(tid<128) tifn[tid]=tif[tid]/tden[tid&7];
  if(tid<64) pn[tid]=protos[tid]/pden[tid>>4];
  __syncthreads();
  if(tid<32){
    int f=tid>>2, t=tid&3;
    float ss=0;
#pragma unroll
    for(int e=0;e<16;e++) ss+=pn[t*16+e]*tifn[e*8+f];
    float u=jax_uniform128(b*32+f*4+t);
    float g=-logf(-logf(u));
    z[tid]=ss+g;
  }
  __syncthreads();
  if(tid<8){
    float best=z[tid*4]; int bi=0;
    for(int t=1;t<4;t++){ float v=z[tid*4+t]; if(v>best){best=v;bi=t;} }
    sidx[tid]=bi;
  }
  __syncthreads();
  if(tid<4){
    int t=tid;
    int fi=0;
    for(int f=7;f>=0;f--) if(sidx[f]==t) fi=f;
    sfirst[t]=fi;
  } else if(tid<12){
    int f=tid-4;
    int c=0; for(int f2=0;f2<f;f2++) if(sidx[f2]==sidx[f]) c++;
    srank[f]=c;
  }
  __syncthreads();

  if(tid<128) fbuf[tid]=te_s[tid];
  else fbuf[tid]=ie[b*128+tid-128];
  __syncthreads();
  if(tid<64){
    float a0=0,a1=0,a2=0,a3=0;
    for(int k=0;k<256;k+=4){
      a0+=fbuf[k]  *bv_w1[k*64+lane];
      a1+=fbuf[k+1]*bv_w1[(k+1)*64+lane];
      a2+=fbuf[k+2]*bv_w1[(k+2)*64+lane];
      a3+=fbuf[k+3]*bv_w1[(k+3)*64+lane];
    }
    float s=bv_b1[lane]+((a0+a1)+(a2+a3));
    float mu=wave_sum64(s)*(1.f/64.f);
    float d=s-mu;
    float var=wave_sum64(d*d)*(1.f/64.f);
    hh[lane]=fmaxf(d*(1.0f/sqrtf(var+1e-5f))*bv_ln_g[lane]+bv_ln_b[lane],0.f);
  }
  __syncthreads();
  {
    int n=tid;
    float a0=0,a1=0;
    for(int k=0;k<64;k+=2){
      a0+=hh[k]*bv_w2[k*256+n];
      a1+=hh[k+1]*bv_w2[(k+1)*256+n];
    }
    ffn_s[n]=bv_b2[n]+a0+a1;
  }
  __syncthreads();
  if(tid<64){
    float sq=0;
#pragma unroll
    for(int u=0;u<4;u++){ float v=ffn_s[u*64+lane]; sq+=v*v; }
    sq=wave_sum64(sq);
    if(lane==0) finv_s=1.0f/fmaxf(sqrtf(sq),1e-12f);
  }
  __syncthreads();
  ffn_s[tid]*=finv_s;
  __syncthreads();

  if(tid<64){
    int t=tid>>4, v=tid&15;
    int tt=sidx[sfirst[t]];
    const float4* row=(const float4*)(bank+(tt*16+v)*256);
    float sa=0,sb=0,na=0,nb=0;
    for(int d4=0;d4<64;d4+=2){
      float4 r1=row[d4], r2=row[d4+1];
      const float* f1p=&ffn_s[d4*4];
      sa+=f1p[0]*r1.x+f1p[1]*r1.y+f1p[2]*r1.z+f1p[3]*r1.w;
      na+=r1.x*r1.x+r1.y*r1.y+r1.z*r1.z+r1.w*r1.w;
      sb+=f1p[4]*r2.x+f1p[5]*r2.y+f1p[6]*r2.z+f1p[7]*r2.w;
      nb+=r2.x*r2.x+r2.y*r2.y+r2.z*r2.z+r2.w*r2.w;
    }
    scores[tid]=(sa+sb)/fmaxf(sqrtf(na+nb),1e-12f);
  }
  __syncthreads();
  if(tid<4){
    const float* sc=&scores[tid*16];
    unsigned used=0;
    for(int pk=0;pk<16;pk++){
      int best=-1; float bv=-1e30f;
      for(int v2=0;v2<16;v2++){
        if(used&(1u<<v2)) continue;
        float vv=sc[v2];
        if(best<0||vv>bv){bv=vv;best=v2;}
      }
      used|=1u<<best;
      order[tid*16+pk]=best;
    }
  }
  __syncthreads();
  if(tid<8){
    int t=sidx[tid];
    int v=order[t*16+srank[tid]];
    rows[tid]=t*16+v;
    idxo[b*8+tid]=t;
  }
  __syncthreads();

  for(int ii=tid;ii<2048;ii+=256){
    int r=ii>>8, d=ii&255;
    bvf[ii]=bank[rows[r]*256+d];
  }
  __syncthreads();
  for(int it=0;it<2;it++){
    int r=wv*2+it;
    const float* bp=&bvf[r*256];
    float a0=0,a1=0,a2=0,a3=0;
    float c0=0,c1=0,c2=0,c3=0;
    for(int d=0;d<256;d+=4){
      float b0=bp[d],b1=bp[d+1],b2=bp[d+2],b3=bp[d+3];
      a0+=b0*m1_w1[d*64+lane];
      a1+=b1*m1_w1[(d+1)*64+lane];
      a2+=b2*m1_w1[(d+2)*64+lane];
      a3+=b3*m1_w1[(d+3)*64+lane];
      c0+=b0*m3_w1[d*64+lane];
      c1+=b1*m3_w1[(d+1)*64+lane];
      c2+=b2*m3_w1[(d+2)*64+lane];
      c3+=b3*m3_w1[(d+3)*64+lane];
    }
    float s1=m1_b1[lane]+((a0+a1)+(a2+a3));
    float s3=m3_b1[lane]+((c0+c1)+(c2+c3));
    float mu=wave_sum64(s1)*(1.f/64.f);
    float dd=s1-mu;
    float var=wave_sum64(dd*dd)*(1.f/64.f);
    hid1[(b*8+r)*64+lane]=fmaxf(dd*(1.0f/sqrtf(var+1e-5f))*m1_g[lane]+m1_bb[lane],0.f);
    mu=wave_sum64(s3)*(1.f/64.f);
    dd=s3-mu;
    var=wave_sum64(dd*dd)*(1.f/64.f);
    hid3[(b*8+r)*64+lane]=fmaxf(dd*(1.0f/sqrtf(var+1e-5f))*m3_g[lane]+m3_bb[lane],0.f);
  }
}

// ---------------- k_heads ----------------
__global__ __launch_bounds__(256) void k_heads(const float* __restrict__ hid1, const float* __restrict__ hid3,
                        const float* __restrict__ w2a, const float* __restrict__ b2a,
                        const float* __restrict__ w2b, const float* __restrict__ b2b,
                        unsigned short* __restrict__ A1, unsigned short* __restrict__ A3){
  __shared__ float hl[2048];
  if(blockIdx.x<16){
    int n=blockIdx.x*256+threadIdx.x;
    for(int i=threadIdx.x;i<2048;i+=256) hl[i]=hid1[i];
    __syncthreads();
    float wcol[64];
#pragma unroll
    for(int k=0;k<64;k++) wcol[k]=w2a[k*4096+n];
    float bb=b2a[n];
    for(int bf=0;bf<32;bf++){
      float s=bb;
#pragma unroll
      for(int k=0;k<64;k++) s+=hl[bf*64+k]*wcol[k];
      A1[bf*4096+n]=f2bf(s);
    }
  } else {
    int n=(blockIdx.x-16)*256+threadIdx.x;
    for(int i=threadIdx.x;i<2048;i+=256) hl[i]=hid3[i];
    __syncthreads();
    float wcol[64];
#pragma unroll
    for(int k=0;k<64;k++) wcol[k]=w2b[(size_t)k*36864+n];
    float bb=b2b[n];
    int o=n/576, rem=n-o*576;
    int c=rem/9, tap=rem-c*9;
    size_t base=((size_t)tap*64+o)*64+c;
    for(int bf=0;bf<32;bf++){
      float s=bb;
#pragma unroll
      for(int k=0;k<64;k++) s+=hl[bf*64+k]*wcol[k];
      A3[(size_t)bf*9*4096+base]=f2bf(s);
    }
  }
}

// ---------------- fused dynamic conv: 512 threads, f-halves across wave groups, LDS-atomic f-mean ----------------
__global__ __launch_bounds__(512) void k_dynF(const unsigned short* __restrict__ imgTP,
                       const unsigned short* __restrict__ A1, const unsigned short* __restrict__ A3,
                       const int* __restrict__ idx, const float* __restrict__ bn,
                       const float* __restrict__ zc_w, const float* __restrict__ zc_b,
                       const float* __restrict__ img, float* __restrict__ out){
  int blk=blockIdx.x;
  int b=blk/48, r0=blk-b*48;
  int tid=threadIdx.x;
  int lane=tid&63, w8=tid>>6;
  int mt=w8&3, fh=w8>>2;
  int n0=lane&15, kg=lane>>4;
  __shared__ float xl[64*50];     // [c][px] stride 50, accumulated across f-halves via LDS atomics
  __shared__ float zl[4096];      // zc_w [o][c]
  for(int i=tid;i<4096;i+=512) zl[i]=zc_w[i];
  for(int i=tid;i<3200;i+=512) xl[i]=0.f;
  __syncthreads();
  const unsigned short* ib=imgTP+(size_t)b*PHW*64;
  int obase=mt*16+kg*4;
  float scale[4],m_[4],be_[4];
#pragma unroll
  for(int reg=0;reg<4;reg++){
    int o=obase+reg;
    scale[reg]=bn[o]/sqrtf(bn[192+o]+1e-5f);
    m_[reg]=bn[128+o]; be_[reg]=bn[64+o];
  }
  float xsum[3][4];
#pragma unroll
  for(int wc=0;wc<3;wc++)
#pragma unroll
    for(int reg=0;reg<4;reg++) xsum[wc][reg]=0.f;
  for(int f=fh*4;f<fh*4+4;f++){
    int bf=b*8+f;
    int tt=idx[bf];
    floatx4 acc[3];
#pragma unroll
    for(int i=0;i<3;i++) acc[i]=(floatx4){0.f,0.f,0.f,0.f};
    if(tt==0){
      const unsigned short* Ab=A1+(size_t)bf*4096;
#pragma unroll
      for(int c0=0;c0<64;c0+=32){
        short8 a=*(const short8*)(Ab+((mt*16+n0)*64+c0+kg*8));
#pragma unroll
        for(int wc=0;wc<3;wc++){
          int poff=(r0+3)*PP + wc*16+n0+3;
          short8 bv=*(const short8*)(ib+((size_t)poff*64+c0+kg*8));
          acc[wc]=__builtin_amdgcn_mfma_f32_16x16x32_bf16(a,bv,acc[wc],0,0,0);
        }
      }
    } else {
      int d=tt;
      const unsigned short* A3b=A3+(size_t)bf*9*4096;
#pragma unroll
      for(int ti=0;ti<3;ti++){
        int r=r0+d*(ti-1)+3;
#pragma unroll
        for(int tj=0;tj<3;tj++){
          int tap=ti*3+tj;
          int dw=d*(tj-1)+3;
          const unsigned short* Ab=A3b+(size_t)tap*4096;
#pragma unroll
          for(int c0=0;c0<64;c0+=32){
            short8 a=*(const short8*)(Ab+((mt*16+n0)*64+c0+kg*8));
#pragma unroll
            for(int wc=0;wc<3;wc++){
              int w=wc*16+n0+dw;
              short8 bv=*(const short8*)(ib+((size_t)(r*PP+w)*64+c0+kg*8));
              acc[wc]=__builtin_amdgcn_mfma_f32_16x16x32_bf16(a,bv,acc[wc],0,0,0);
            }
          }
        }
      }
    }
#pragma unroll
    for(int wc=0;wc<3;wc++)
#pragma unroll
      for(int reg=0;reg<4;reg++)
        xsum[wc][reg]+=leaky((acc[wc][reg]-m_[reg])*scale[reg]+be_[reg]);
  }
#pragma unroll
  for(int wc=0;wc<3;wc++)
#pragma unroll
    for(int reg=0;reg<4;reg++)
      atomicAdd(&xl[(obase+reg)*50 + wc*16+n0], xsum[wc][reg]*0.125f);
  __syncthreads();
  size_t base=(size_t)b*64*HW + r0*48;
  for(int e=tid;e<3072;e+=512){
    int o=e/48, px=e-o*48;
    float s=zc_b[o];
#pragma unroll
    for(int c=0;c<64;c++) s+=zl[o*64+c]*xl[c*50+px];
    size_t a=base+(size_t)o*HW+px;
    out[a]=s+img[a];
  }
}

extern "C" void kernel_launch(void* const* d_in, const int* in_sizes, int n_in,
                              void* d_out, int out_size, void* d_ws, size_t ws_size,
                              hipStream_t stream){
  const float* bank   =(const float*)d_in[0];
  const float* task_f =(const float*)d_in[1];
  const float* img_f  =(const float*)d_in[2];
  const float* protos =(const float*)d_in[3];
  const float* tA_w1  =(const float*)d_in[4];
  const float* tA_w2  =(const float*)d_in[5];
  const float* iA_w   =(const float*)d_in[6];
  const float* iA_bn  =(const float*)d_in[7];
  const float* at_w1  =(const float*)d_in[8];
  const float* at_b1  =(const float*)d_in[9];
  const float* at_ln_g=(const float*)d_in[10];
  const float* at_ln_b=(const float*)d_in[11];
  const float* at_w2  =(const float*)d_in[12];
  const float* at_b2  =(const float*)d_in[13];
  const float* bv_t1  =(const float*)d_in[14];
  const float* bv_t2  =(const float*)d_in[15];
  const float* bv_ic1 =(const float*)d_in[16];
  const float* bv_bn1 =(const float*)d_in[17];
  const float* bv_ic2 =(const float*)d_in[18];
  const float* bv_bn2 =(const float*)d_in[19];
  const float* bv_w1  =(const float*)d_in[20];
  const float* bv_b1  =(const float*)d_in[21];
  const float* bv_ln_g=(const float*)d_in[22];
  const float* bv_ln_b=(const float*)d_in[23];
  const float* bv_w2  =(const float*)d_in[24];
  const float* bv_b2  =(const float*)d_in[25];
  const float* m1_w1  =(const float*)d_in[26];
  const float* m1_b1  =(const float*)d_in[27];
  const float* m1_ln_g=(const float*)d_in[28];
  const float* m1_ln_b=(const float*)d_in[29];
  const float* m1_w2  =(const float*)d_in[30];
  const float* m1_b2  =(const float*)d_in[31];
  const float* m3_w1  =(const float*)d_in[32];
  const float* m3_b1  =(const float*)d_in[33];
  const float* m3_ln_g=(const float*)d_in[34];
  const float* m3_ln_b=(const float*)d_in[35];
  const float* m3_w2  =(const float*)d_in[36];
  const float* m3_b2  =(const float*)d_in[37];
  const float* blr_bn =(const float*)d_in[38];
  const float* zc_w   =(const float*)d_in[39];
  const float* zc_b   =(const float*)d_in[40];

  float* ws=(float*)d_ws;
  float* totA=ws+0;       float* a0A=ws+16;      float* aLA=ws+32;
  float* totB=ws+48;      float* a0B=ws+304;     float* aLB=ws+560;
  float* rmsacc=ws+816;   float* i1 =ws+820;     float* ie =ws+852;   // ..1364
  int*   idxp  =(int*)(ws+2932);
  float* hid1=ws+3044;    float* hid3=ws+5092;
  unsigned short* A1p  =(unsigned short*)(ws+7140);     // 131072 bf16
  unsigned short* A3p  =(unsigned short*)(ws+72676);    // 1179648 bf16
  unsigned short* imgTP=(unsigned short*)(ws+662500);   // 746496 bf16 (padded)
  unsigned short* ie1TP=(unsigned short*)(ws+1035748);  // 746496 bf16 (padded)
  unsigned short* W1Tp =(unsigned short*)(ws+1408996);  // 36864 bf16
  unsigned short* W2Tp =(unsigned short*)(ws+1427428);  // 73728 bf16
  unsigned short* WATp =(unsigned short*)(ws+1464292);  // 9216 bf16
  float* xpart=ws+1468900;                              // 4*128*2304 = 1,179,648 f -> ends 2,648,548
  // total ~10.6 MB

  hipMemsetAsync(ws, 0, 1364*sizeof(float), stream);                 // stats accumulators
  hipMemsetAsync(imgTP, 0, 2*746496*sizeof(unsigned short), stream); // padded halos
  hipMemsetAsync(xpart, 0, 1179648*sizeof(float), stream);           // ic2 conv partials

  k_pre<<<868,256,0,stream>>>(task_f, tA_w1, bv_t1,
                              totA, a0A, aLA, totB, a0B, aLB, rmsacc,
                              img_f, bv_ic1, bv_ic2, iA_w, imgTP, W1Tp, W2Tp, WATp);
  k_conv1<<<216,256,0,stream>>>(imgTP, W1Tp, WATp, bv_bn1, iA_bn, ie1TP, i1);
  k_ic2M<<<dim3(96,2,3),256,0,stream>>>(ie1TP, W2Tp, bv_bn2, xpart);
  k_ic2post<<<512,256,0,stream>>>(xpart, bv_bn2, ie);
  k_mid<<<4,256,0,stream>>>(totA,a0A,aLA,totB,a0B,aLB, rmsacc, tA_w2, bv_t2, i1, ie,
                            at_w1, at_b1, at_ln_g, at_ln_b, at_w2, at_b2, protos,
                            bv_w1, bv_b1, bv_ln_g, bv_ln_b, bv_w2, bv_b2, bank,
                            m1_w1, m1_b1, m1_ln_g, m1_ln_b,
                            m3_w1, m3_b1, m3_ln_g, m3_ln_b,
                            idxp, hid1, hid3);
  k_heads<<<160,256,0,stream>>>(hid1, hid3, m1_w2, m1_b2, m3_w2, m3_b2, A1p, A3p);
  k_dynF<<<192,512,0,stream>>>(imgTP, A1p, A3p, idxp, blr_bn, zc_w, zc_b, img_f, (float*)d_out);

  (void)in_sizes; (void)n_in; (void)out_size; (void)ws_size;
}

// Round 11
// 291.951 us; speedup vs baseline: 1.2137x; 1.2137x over previous
//
#include <hip/hip_runtime.h>
#include <math.h>

#define LEAKC 0.2f

#define NB 4
#define NC 64
#define LLEN 16384
#define HW 2304
#define PP 54          // padded pitch (48 + 2*3)
#define PHW 2916       // 54*54

typedef __attribute__((ext_vector_type(8))) short short8;
typedef __attribute__((ext_vector_type(4))) float floatx4;

__device__ __forceinline__ float leaky(float x){ return x > 0.f ? x : LEAKC*x; }

__device__ __forceinline__ float wave_sum64(float v){
  for(int off=32;off;off>>=1) v += __shfl_xor(v,off);
  return v;
}

__device__ __forceinline__ unsigned short f2bf(float x){
  unsigned u=__float_as_uint(x);
  unsigned r=u+0x7FFFu+((u>>16)&1u);
  return (unsigned short)(r>>16);
}

__device__ __forceinline__ void threefry2x32(unsigned k0, unsigned k1, unsigned& x0, unsigned& x1){
  unsigned ks0=k0, ks1=k1, ks2=k0^k1^0x1BD11BDAu;
  x0+=ks0; x1+=ks1;
  const int rot0[4]={13,15,26,6};
  const int rot1[4]={17,29,16,24};
#define TF_APPLY(rr) {for(int r=0;r<4;r++){x0+=x1; x1=(x1<<rr[r])|(x1>>(32-rr[r])); x1^=x0;}}
  TF_APPLY(rot0); x0+=ks1; x1+=ks2+1u;
  TF_APPLY(rot1); x0+=ks2; x1+=ks0+2u;
  TF_APPLY(rot0); x0+=ks0; x1+=ks1+3u;
  TF_APPLY(rot1); x0+=ks1; x1+=ks2+4u;
  TF_APPLY(rot0); x0+=ks2; x1+=ks0+5u;
#undef TF_APPLY
}

__device__ __forceinline__ float jax_uniform128(int i){
  unsigned x0=0u, x1=(unsigned)i;
  threefry2x32(0u,42u,x0,x1);
  unsigned bits = x0 ^ x1;
  unsigned fb=(bits>>9)|0x3f800000u;
  float f=__uint_as_float(fb)-1.0f;
  float u=f*(1.0f-1e-10f)+1e-10f;
  return fmaxf(1e-10f,u);
}

// ---------------- k_pre: stats (0..255) + padded imgT transpose (256..399) + weight prep (400..867) ----------------
__global__ __launch_bounds__(256) void k_pre(const float* __restrict__ task_f,
                      const float* __restrict__ w1A, const float* __restrict__ w1B,
                      float* __restrict__ totA, float* __restrict__ a0A, float* __restrict__ aLA,
                      float* __restrict__ totB, float* __restrict__ a0B, float* __restrict__ aLB,
                      float* __restrict__ rmsacc,
                      const float* __restrict__ img,
                      const float* __restrict__ w1, const float* __restrict__ w2,
                      const float* __restrict__ wa,
                      unsigned short* __restrict__ imgTP,
                      unsigned short* __restrict__ W1T, unsigned short* __restrict__ W2T,
                      unsigned short* __restrict__ WAT){
  if(blockIdx.x<256){
    int b=blockIdx.x>>6, seg=blockIdx.x&63;
    const float* x=task_f+b*LLEN;
    float tA[4]={0,0,0,0};
    float tB[64];
#pragma unroll
    for(int c=0;c<64;c++) tB[c]=0.f;
    float sq=0.f;
    int l=seg*256+threadIdx.x;
    {
      float xm=(l>0)?x[l-1]:0.f;
      float xc=x[l];
      float xp=(l<LLEN-1)?x[l+1]:0.f;
      sq=xc*xc;
#pragma unroll
      for(int c=0;c<4;c++){
        float a=leaky(w1A[c*3+0]*xm + w1A[c*3+1]*xc + w1A[c*3+2]*xp);
        tA[c]=a;
        if(l==0) a0A[b*4+c]=a;
        if(l==LLEN-1) aLA[b*4+c]=a;
      }
#pragma unroll
      for(int c=0;c<64;c++){
        float a=leaky(w1B[c*3+0]*xm + w1B[c*3+1]*xc + w1B[c*3+2]*xp);
        tB[c]=a;
        if(l==0) a0B[b*64+c]=a;
        if(l==LLEN-1) aLB[b*64+c]=a;
      }
    }
    sq=wave_sum64(sq);
#pragma unroll
    for(int c=0;c<4;c++) tA[c]=wave_sum64(tA[c]);
#pragma unroll
    for(int c=0;c<64;c++){
      float v=tB[c];
      for(int off=32;off;off>>=1) v+=__shfl_down(v,off);
      tB[c]=v;
    }
    __shared__ float redB[4][64];
    __shared__ float redA[4][4];
    __shared__ float redQ[4];
    int wave=threadIdx.x>>6, lane=threadIdx.x&63;
    if(lane==0){
#pragma unroll
      for(int c=0;c<64;c++) redB[wave][c]=tB[c];
#pragma unroll
      for(int c=0;c<4;c++) redA[wave][c]=tA[c];
      redQ[wave]=sq;
    }
    __syncthreads();
    if(threadIdx.x<64){
      float s=redB[0][threadIdx.x]+redB[1][threadIdx.x]+redB[2][threadIdx.x]+redB[3][threadIdx.x];
      atomicAdd(&totB[b*64+threadIdx.x], s);
    } else if(threadIdx.x<68){
      int c=threadIdx.x-64;
      float s=redA[0][c]+redA[1][c]+redA[2][c]+redA[3][c];
      atomicAdd(&totA[b*4+c], s);
    } else if(threadIdx.x==68){
      atomicAdd(&rmsacc[b], redQ[0]+redQ[1]+redQ[2]+redQ[3]);
    }
  } else if(blockIdx.x<400){
    int blk=blockIdx.x-256;
    int b=blk/36, t=blk%36;
    int p0=t*64;
    __shared__ float tile[64][65];
    int pp=threadIdx.x&63, c4=threadIdx.x>>6;
    for(int r=0;r<16;r++){
      int c=c4*16+r;
      tile[c][pp]=img[(b*64+c)*HW + p0+pp];
    }
    __syncthreads();
    int pxl=threadIdx.x>>2, cg=(threadIdx.x&3)*16;
    unsigned out[8];
#pragma unroll
    for(int q=0;q<8;q++){
      unsigned lo=f2bf(tile[cg+2*q][pxl]);
      unsigned hi=f2bf(tile[cg+2*q+1][pxl]);
      out[q]=lo|(hi<<16);
    }
    int px=p0+pxl;
    int h=px/48, w=px-h*48;
    int poff=(h+3)*PP+(w+3);
    unsigned* dst=(unsigned*)(imgTP + ((size_t)(b*PHW+poff))*64 + cg);
#pragma unroll
    for(int q=0;q<8;q++) dst[q]=out[q];
  } else {
    int n=(blockIdx.x-400)*256+threadIdx.x;
    if(n<9*64*64){
      int tap=n>>12, oc=(n>>6)&63, c=n&63;
      W1T[n]=f2bf(w1[oc*576+c*9+tap]);
    } else if(n<9*64*64+9*128*64){
      int m=n-9*64*64;
      int tap=m/8192, r=m-tap*8192, oc=r>>6, c=r&63;
      W2T[m]=f2bf(w2[oc*576+c*9+tap]);
    } else {
      int q=n-9*64*64-9*128*64;
      if(q<9*16*64){
        int tap=q>>10, r=q&1023, o=r>>6, c=r&63;
        WAT[q]=(o<8)?f2bf(wa[o*576+c*9+tap]):(unsigned short)0;
      }
    }
  }
}

// ---------------- k_conv1: ic1 MFMA (0..95, two rows/block) + iA MFMA mean (96..119) ----------------
__global__ __launch_bounds__(256) void k_conv1(const unsigned short* __restrict__ imgTP,
                        const unsigned short* __restrict__ W1T,
                        const unsigned short* __restrict__ WAT,
                        const float* __restrict__ bn1, const float* __restrict__ bnA,
                        unsigned short* __restrict__ ie1TP, float* __restrict__ i1){
  int lane=threadIdx.x&63, mt=threadIdx.x>>6;
  int n0=lane&15, kg=lane>>4;
  if(blockIdx.x<96){
    int blk=blockIdx.x;
    int b=blk/24, hp=blk-b*24;
    int h0=hp*2;
    const unsigned short* ib=imgTP+(size_t)b*PHW*64;
    floatx4 acc[6];
#pragma unroll
    for(int i=0;i<6;i++) acc[i]=(floatx4){0.f,0.f,0.f,0.f};
#pragma unroll
    for(int ti=0;ti<3;ti++){
#pragma unroll
      for(int tj=0;tj<3;tj++){
        int tap=ti*3+tj;
        const unsigned short* Ab=W1T+(size_t)tap*4096;
#pragma unroll
        for(int c0=0;c0<64;c0+=32){
          short8 a=*(const short8*)(Ab+((mt*16+n0)*64+c0+kg*8));
#pragma unroll
          for(int rr=0;rr<2;rr++){
            int r=h0+rr+ti-1+3;
#pragma unroll
            for(int wc=0;wc<3;wc++){
              int w=wc*16+n0+tj-1+3;
              short8 bv=*(const short8*)(ib+((size_t)(r*PP+w)*64+c0+kg*8));
              acc[rr*3+wc]=__builtin_amdgcn_mfma_f32_16x16x32_bf16(a,bv,acc[rr*3+wc],0,0,0);
            }
          }
        }
      }
    }
    int obase=mt*16+kg*4;
    float scale[4],m_[4],be_[4];
#pragma unroll
    for(int reg=0;reg<4;reg++){
      int o=obase+reg;
      scale[reg]=bn1[o]/sqrtf(bn1[192+o]+1e-5f);
      m_[reg]=bn1[128+o]; be_[reg]=bn1[64+o];
    }
#pragma unroll
    for(int rr=0;rr<2;rr++){
#pragma unroll
      for(int wc=0;wc<3;wc++){
        int poff=(h0+rr+3)*PP + wc*16+n0+3;
        float v0=leaky((acc[rr*3+wc][0]-m_[0])*scale[0]+be_[0]);
        float v1=leaky((acc[rr*3+wc][1]-m_[1])*scale[1]+be_[1]);
        float v2=leaky((acc[rr*3+wc][2]-m_[2])*scale[2]+be_[2]);
        float v3=leaky((acc[rr*3+wc][3]-m_[3])*scale[3]+be_[3]);
        unsigned w0=f2bf(v0)|((unsigned)f2bf(v1)<<16);
        unsigned w1=f2bf(v2)|((unsigned)f2bf(v3)<<16);
        uint2 pk={w0,w1};
        *(uint2*)(ie1TP+((size_t)(b*PHW+poff)*64+obase))=pk;
      }
    }
  } else {
    int blk=blockIdx.x-96;
    int b=blk/6, hg=blk%6;
    int hp=hg*4+mt;
    int h0=hp*2;
    const unsigned short* ib=imgTP+(size_t)b*PHW*64;
    floatx4 acc[6];
#pragma unroll
    for(int i=0;i<6;i++) acc[i]=(floatx4){0.f,0.f,0.f,0.f};
#pragma unroll
    for(int ti=0;ti<3;ti++){
#pragma unroll
      for(int tj=0;tj<3;tj++){
        int tap=ti*3+tj;
        const unsigned short* Ab=WAT+(size_t)tap*1024;
#pragma unroll
        for(int c0=0;c0<64;c0+=32){
          short8 a=*(const short8*)(Ab+(n0*64+c0+kg*8));
#pragma unroll
          for(int rr=0;rr<2;rr++){
            int r=h0+rr+ti-1+3;
#pragma unroll
            for(int wc=0;wc<3;wc++){
              int w=wc*16+n0+tj-1+3;
              short8 bv=*(const short8*)(ib+((size_t)(r*PP+w)*64+c0+kg*8));
              acc[rr*3+wc]=__builtin_amdgcn_mfma_f32_16x16x32_bf16(a,bv,acc[rr*3+wc],0,0,0);
            }
          }
        }
      }
    }
    int obase=kg*4;
#pragma unroll
    for(int reg=0;reg<4;reg++){
      int o=obase+reg;
      float part=0;
      if(o<8){
        float scale=bnA[o]/sqrtf(bnA[24+o]+1e-5f);
        float m_=bnA[16+o], be_=bnA[8+o];
#pragma unroll
        for(int i=0;i<6;i++) part+=leaky((acc[i][reg]-m_)*scale+be_);
      }
      for(int off=1;off<16;off<<=1) part+=__shfl_xor(part,off);
      if(n0==0 && o<8) atomicAdd(&i1[b*8+o], part*(1.f/2304.f));
    }
  }
}

// ---------------- bv_ic2 conv via MFMA + mean, branchless via padded input (R9 fused form) ----------------
__global__ __launch_bounds__(256) void k_ic2M(const unsigned short* __restrict__ ie1TP,
                       const unsigned short* __restrict__ W2T,
                       const float* __restrict__ bn, float* __restrict__ ie){
  int blk=blockIdx.x;
  int b=blk/24, hp=blk-b*24;
  int mo=blockIdx.y*64;
  int lane=threadIdx.x&63, mt=threadIdx.x>>6;
  int n0=lane&15, kg=lane>>4;
  int h0=hp*2;
  const unsigned short* ib=ie1TP+(size_t)b*PHW*64;
  floatx4 acc[6];
#pragma unroll
  for(int i=0;i<6;i++) acc[i]=(floatx4){0.f,0.f,0.f,0.f};
#pragma unroll
  for(int ti=0;ti<3;ti++){
#pragma unroll
    for(int tj=0;tj<3;tj++){
      int tap=ti*3+tj;
      const unsigned short* Ab=W2T+(size_t)tap*8192;
#pragma unroll
      for(int c0=0;c0<64;c0+=32){
        short8 a=*(const short8*)(Ab+((mo+mt*16+n0)*64+c0+kg*8));
#pragma unroll
        for(int rr=0;rr<2;rr++){
          int r=h0+rr+ti-1+3;
#pragma unroll
          for(int wc=0;wc<3;wc++){
            int w=wc*16+n0+tj-1+3;
            short8 bv=*(const short8*)(ib+((size_t)(r*PP+w)*64+c0+kg*8));
            acc[rr*3+wc]=__builtin_amdgcn_mfma_f32_16x16x32_bf16(a,bv,acc[rr*3+wc],0,0,0);
          }
        }
      }
    }
  }
  int obase=mo+mt*16+kg*4;
#pragma unroll
  for(int reg=0;reg<4;reg++){
    int o=obase+reg;
    float scale=bn[o]/sqrtf(bn[384+o]+1e-5f);
    float m_=bn[256+o], be_=bn[128+o];
    float part=0;
#pragma unroll
    for(int i=0;i<6;i++) part+=leaky((acc[i][reg]-m_)*scale+be_);
    for(int off=1;off<16;off<<=1) part+=__shfl_xor(part,off);
    if(n0==0) atomicAdd(&ie[b*128+o], part*(1.f/2304.f));
  }
}

// ---------------- fused mid, PER-BATCH block (grid=4) ----------------
__global__ __launch_bounds__(256) void k_mid(
    const float* __restrict__ totA, const float* __restrict__ a0A, const float* __restrict__ aLA,
    const float* __restrict__ totB, const float* __restrict__ a0B, const float* __restrict__ aLB,
    const float* __restrict__ rmsacc,
    const float* __restrict__ tA_w2, const float* __restrict__ bv_t2,
    const float* __restrict__ i1, const float* __restrict__ ie,
    const float* __restrict__ at_w1, const float* __restrict__ at_b1,
    const float* __restrict__ at_ln_g, const float* __restrict__ at_ln_b,
    const float* __restrict__ at_w2, const float* __restrict__ at_b2,
    const float* __restrict__ protos,
    const float* __restrict__ bv_w1, const float* __restrict__ bv_b1,
    const float* __restrict__ bv_ln_g, const float* __restrict__ bv_ln_b,
    const float* __restrict__ bv_w2, const float* __restrict__ bv_b2,
    const float* __restrict__ bank,
    const float* __restrict__ m1_w1, const float* __restrict__ m1_b1,
    const float* __restrict__ m1_g,  const float* __restrict__ m1_bb,
    const float* __restrict__ m3_w1, const float* __restrict__ m3_b1,
    const float* __restrict__ m3_g,  const float* __restrict__ m3_bb,
    int* __restrict__ idxo, float* __restrict__ hid1, float* __restrict__ hid3){
  int b=blockIdx.x;
  int tid=threadIdx.x;
  int lane=tid&63, wv=tid>>6;
  const float invL=1.0f/16384.0f;
  __shared__ float sT[64], s0[64], sL[64];
  __shared__ float te_s[128], t1_s[8];
  __shared__ float f1[16], h[64], tif[128], tifn[128], tden[8], pden[4], pn[64], z[32];
  __shared__ int sidx[8], sfirst[4], srank[8], rows[8];
  __shared__ float fbuf[256], hh[64], ffn_s[256], finv_s;
  __shared__ float scores[64];
  __shared__ int order[64];
  __shared__ float bvf[2048];

  if(tid<64){ sT[tid]=totB[b*64+tid]; s0[tid]=a0B[b*64+tid]; sL[tid]=aLB[b*64+tid]; }
  __syncthreads();
  float scB=1.0f/(sqrtf(rmsacc[b]*invL)+1e-8f);
  if(tid<128){
    int c2=tid;
    const float* wr=bv_t2+c2*192;
    float s=0;
    for(int c1=0;c1<64;c1+=8){
      float4 q[6];
      const float4* r4=(const float4*)(wr+c1*3);
#pragma unroll
      for(int u=0;u<6;u++) q[u]=r4[u];
      const float* qq=(const float*)q;
#pragma unroll
      for(int u=0;u<8;u++){
        int c=c1+u;
        float T=sT[c], A0=s0[c], AL=sL[c];
        s += qq[u*3+0]*(T-AL) + qq[u*3+1]*T + qq[u*3+2]*(T-A0);
      }
    }
    te_s[c2]=s*invL*scB;
  } else if(tid<136){
    int c2=tid-128;
    float s=0;
    for(int c1=0;c1<4;c1++){
      float T=totA[b*4+c1], A0=a0A[b*4+c1], AL=aLA[b*4+c1];
      const float* w=&tA_w2[(c2*4+c1)*3];
      s += w[0]*(T-AL) + w[1]*T + w[2]*(T-A0);
    }
    t1_s[c2]=s*invL;
  }
  __syncthreads();

  if(tid<8) f1[tid]=t1_s[tid];
  else if(tid<16) f1[tid]=i1[b*8+tid-8];
  __syncthreads();
  if(tid<64){
    float s=at_b1[lane];
#pragma unroll
    for(int i=0;i<16;i++) s+=f1[i]*at_w1[i*64+lane];
    float mu=wave_sum64(s)*(1.f/64.f);
    float d=s-mu;
    float var=wave_sum64(d*d)*(1.f/64.f);
    h[lane]=fmaxf(d*(1.0f/sqrtf(var+1e-5f))*at_ln_g[lane]+at_ln_b[lane],0.f);
  }
  __syncthreads();
  if(tid<128){
    int n=tid;
    float a0=0,a1=0;
    for(int k=0;k<64;k+=2){
      a0+=h[k]*at_w2[k*128+n];
      a1+=h[k+1]*at_w2[(k+1)*128+n];
    }
    tif[n]=at_b2[n]+a0+a1;
  }
  __syncthreads();
  if(tid<8){
    int f=tid;
    float ss=0; for(int e=0;e<16;e++){float v=tif[e*8+f]; ss+=v*v;}
    tden[f]=fmaxf(sqrtf(ss),1e-8f);
  } else if(tid<12){
    int t=tid-8;
    float ss=0; for(int e=0;e<16;e++){float v=protos[t*16+e]; ss+=v*v;}
    pden[t]=fmaxf(sqrtf(ss),1e-8f);
  }
  __syncthreads();
  if(tid<128) tifn[tid]=tif[tid]/tden[tid&7];
  if(tid<64) pn[tid]=protos[tid]/pden[tid>>4];
  __syncthreads();
  if(tid<32){
    int f=tid>>2, t=tid&3;
    float ss=0;
#pragma unroll
    for(int e=0;e<16;e++) ss+=pn[t*16+e]*tifn[e*8+f];
    float u=jax_uniform128(b*32+f*4+t);
    float g=-logf(-logf(u));
    z[tid]=ss+g;
  }
  __syncthreads();
  if(tid<8){
    float best=z[tid*4]; int bi=0;
    for(int t=1;t<4;t++){ float v=z[tid*4+t]; if(v>best){best=v;bi=t;} }
    sidx[tid]=bi;
  }
  __syncthreads();
  if(tid<4){
    int t=tid;
    int fi=0;
    for(int f=7;f>=0;f--) if(sidx[f]==t) fi=f;
    sfirst[t]=fi;
  } else if(tid<12){
    int f=tid-4;
    int c=0; for(int f2=0;f2<f;f2++) if(sidx[f2]==sidx[f]) c++;
    srank[f]=c;
  }
  __syncthreads();

  if(tid<128) fbuf[tid]=te_s[tid];
  else fbuf[tid]=ie[b*128+tid-128];
  __syncthreads();
  if(tid<64){
    float a0=0,a1=0,a2=0,a3=0;
    for(int k=0;k<256;k+=4){
      a0+=fbuf[k]  *bv_w1[k*64+lane];
      a1+=fbuf[k+1]*bv_w1[(k+1)*64+lane];
      a2+=fbuf[k+2]*bv_w1[(k+2)*64+lane];
      a3+=fbuf[k+3]*bv_w1[(k+3)*64+lane];
    }
    float s=bv_b1[lane]+((a0+a1)+(a2+a3));
    float mu=wave_sum64(s)*(1.f/64.f);
    float d=s-mu;
    float var=wave_sum64(d*d)*(1.f/64.f);
    hh[lane]=fmaxf(d*(1.0f/sqrtf(var+1e-5f))*bv_ln_g[lane]+bv_ln_b[lane],0.f);
  }
  __syncthreads();
  {
    int n=tid;
    float a0=0,a1=0;
    for(int k=0;k<64;k+=2){
      a0+=hh[k]*bv_w2[k*256+n];
      a1+=hh[k+1]*bv_w2[(k+1)*256+n];
    }
    ffn_s[n]=bv_b2[n]+a0+a1;
  }
  __syncthreads();
  if(tid<64){
    float sq=0;
#pragma unroll
    for(int u=0;u<4;u++){ float v=ffn_s[u*64+lane]; sq+=v*v; }
    sq=wave_sum64(sq);
    if(lane==0) finv_s=1.0f/fmaxf(sqrtf(sq),1e-12f);
  }
  __syncthreads();
  ffn_s[tid]*=finv_s;
  __syncthreads();

  if(tid<64){
    int t=tid>>4, v=tid&15;
    int tt=sidx[sfirst[t]];
    const float4* row=(const float4*)(bank+(tt*16+v)*256);
    float sa=0,sb=0,na=0,nb=0;
    for(int d4=0;d4<64;d4+=2){
      float4 r1=row[d4], r2=row[d4+1];
      const float* f1p=&ffn_s[d4*4];
      sa+=f1p[0]*r1.x+f1p[1]*r1.y+f1p[2]*r1.z+f1p[3]*r1.w;
      na+=r1.x*r1.x+r1.y*r1.y+r1.z*r1.z+r1.w*r1.w;
      sb+=f1p[4]*r2.x+f1p[5]*r2.y+f1p[6]*r2.z+f1p[7]*r2.w;
      nb+=r2.x*r2.x+r2.y*r2.y+r2.z*r2.z+r2.w*r2.w;
    }
    scores[tid]=(sa+sb)/fmaxf(sqrtf(na+nb),1e-12f);
  }
  __syncthreads();
  if(tid<4){
    const float* sc=&scores[tid*16];
    unsigned used=0;
    for(int pk=0;pk<16;pk++){
      int best=-1; float bv=-1e30f;
      for(int v2=0;v2<16;v2++){
        if(used&(1u<<v2)) continue;
        float vv=sc[v2];
        if(best<0||vv>bv){bv=vv;best=v2;}
      }
      used|=1u<<best;
      order[tid*16+pk]=best;
    }
  }
  __syncthreads();
  if(tid<8){
    int t=sidx[tid];
    int v=order[t*16+srank[tid]];
    rows[tid]=t*16+v;
    idxo[b*8+tid]=t;
  }
  __syncthreads();

  for(int ii=tid;ii<2048;ii+=256){
    int r=ii>>8, d=ii&255;
    bvf[ii]=bank[rows[r]*256+d];
  }
  __syncthreads();
  for(int it=0;it<2;it++){
    int r=wv*2+it;
    const float* bp=&bvf[r*256];
    float a0=0,a1=0,a2=0,a3=0;
    float c0=0,c1=0,c2=0,c3=0;
    for(int d=0;d<256;d+=4){
      float b0=bp[d],b1=bp[d+1],b2=bp[d+2],b3=bp[d+3];
      a0+=b0*m1_w1[d*64+lane];
      a1+=b1*m1_w1[(d+1)*64+lane];
      a2+=b2*m1_w1[(d+2)*64+lane];
      a3+=b3*m1_w1[(d+3)*64+lane];
      c0+=b0*m3_w1[d*64+lane];
      c1+=b1*m3_w1[(d+1)*64+lane];
      c2+=b2*m3_w1[(d+2)*64+lane];
      c3+=b3*m3_w1[(d+3)*64+lane];
    }
    float s1=m1_b1[lane]+((a0+a1)+(a2+a3));
    float s3=m3_b1[lane]+((c0+c1)+(c2+c3));
    float mu=wave_sum64(s1)*(1.f/64.f);
    float dd=s1-mu;
    float var=wave_sum64(dd*dd)*(1.f/64.f);
    hid1[(b*8+r)*64+lane]=fmaxf(dd*(1.0f/sqrtf(var+1e-5f))*m1_g[lane]+m1_bb[lane],0.f);
    mu=wave_sum64(s3)*(1.f/64.f);
    dd=s3-mu;
    var=wave_sum64(dd*dd)*(1.f/64.f);
    hid3[(b*8+r)*64+lane]=fmaxf(dd*(1.0f/sqrtf(var+1e-5f))*m3_g[lane]+m3_bb[lane],0.f);
  }
}

// ---------------- k_heads ----------------
__global__ __launch_bounds__(256) void k_heads(const float* __restrict__ hid1, const float* __restrict__ hid3,
                        const float* __restrict__ w2a, const float* __restrict__ b2a,
                        const float* __restrict__ w2b, const float* __restrict__ b2b,
                        unsigned short* __restrict__ A1, unsigned short* __restrict__ A3){
  __shared__ float hl[2048];
  if(blockIdx.x<16){
    int n=blockIdx.x*256+threadIdx.x;
    for(int i=threadIdx.x;i<2048;i+=256) hl[i]=hid1[i];
    __syncthreads();
    float wcol[64];
#pragma unroll
    for(int k=0;k<64;k++) wcol[k]=w2a[k*4096+n];
    float bb=b2a[n];
    for(int bf=0;bf<32;bf++){
      float s=bb;
#pragma unroll
      for(int k=0;k<64;k++) s+=hl[bf*64+k]*wcol[k];
      A1[bf*4096+n]=f2bf(s);
    }
  } else {
    int n=(blockIdx.x-16)*256+threadIdx.x;
    for(int i=threadIdx.x;i<2048;i+=256) hl[i]=hid3[i];
    __syncthreads();
    float wcol[64];
#pragma unroll
    for(int k=0;k<64;k++) wcol[k]=w2b[(size_t)k*36864+n];
    float bb=b2b[n];
    int o=n/576, rem=n-o*576;
    int c=rem/9, tap=rem-c*9;
    size_t base=((size_t)tap*64+o)*64+c;
    for(int bf=0;bf<32;bf++){
      float s=bb;
#pragma unroll
      for(int k=0;k<64;k++) s+=hl[bf*64+k]*wcol[k];
      A3[(size_t)bf*9*4096+base]=f2bf(s);
    }
  }
}

// ---------------- fused dynamic conv: LDS-staged image slab, 512 thr, f-halves, zc+residual ----------------
#define SLABP 72   // c-pitch in slab (64 + 8) -> rotates banks, 2-way max
__global__ __launch_bounds__(512) void k_dynF(const unsigned short* __restrict__ imgTP,
                       const unsigned short* __restrict__ A1, const unsigned short* __restrict__ A3,
                       const int* __restrict__ idx, const float* __restrict__ bn,
                       const float* __restrict__ zc_w, const float* __restrict__ zc_b,
                       const float* __restrict__ img, float* __restrict__ out){
  int blk=blockIdx.x;
  int b=blk/48, r0=blk-b*48;
  int tid=threadIdx.x;
  int lane=tid&63, w8=tid>>6;
  int mt=w8&3, fh=w8>>2;
  int n0=lane&15, kg=lane>>4;
  __shared__ unsigned short slab[7*54*SLABP];  // rows r0..r0+6 (padded coords) x 54 w x 64 c
  __shared__ float xl[64*50];
  __shared__ float zl[4096];
  for(int i=tid;i<4096;i+=512) zl[i]=zc_w[i];
  for(int i=tid;i<3200;i+=512) xl[i]=0.f;
  // stage the 7-row slab (global, coalesced 16B) -> LDS
  {
    const unsigned short* ibase=imgTP+((size_t)b*PHW+(size_t)r0*PP)*64;
    for(int e=tid;e<7*54*8;e+=512){
      int rr=e/(54*8), rem=e-rr*54*8, w=rem>>3, ck=rem&7;
      uint4 v=*(const uint4*)(ibase + ((size_t)(rr*PP+w))*64 + ck*8);
      *(uint4*)(slab + (rr*54+w)*SLABP + ck*8)=v;
    }
  }
  __syncthreads();
  int obase=mt*16+kg*4;
  float scale[4],m_[4],be_[4];
#pragma unroll
  for(int reg=0;reg<4;reg++){
    int o=obase+reg;
    scale[reg]=bn[o]/sqrtf(bn[192+o]+1e-5f);
    m_[reg]=bn[128+o]; be_[reg]=bn[64+o];
  }
  float xsum[3][4];
#pragma unroll
  for(int wc=0;wc<3;wc++)
#pragma unroll
    for(int reg=0;reg<4;reg++) xsum[wc][reg]=0.f;
  for(int f=fh*4;f<fh*4+4;f++){
    int bf=b*8+f;
    int tt=idx[bf];
    floatx4 acc[3];
#pragma unroll
    for(int i=0;i<3;i++) acc[i]=(floatx4){0.f,0.f,0.f,0.f};
    if(tt==0){
      const unsigned short* Ab=A1+(size_t)bf*4096;
#pragma unroll
      for(int c0=0;c0<64;c0+=32){
        short8 a=*(const short8*)(Ab+((mt*16+n0)*64+c0+kg*8));
#pragma unroll
        for(int wc=0;wc<3;wc++){
          short8 bv=*(const short8*)(slab + (3*54 + wc*16+n0+3)*SLABP + c0+kg*8);
          acc[wc]=__builtin_amdgcn_mfma_f32_16x16x32_bf16(a,bv,acc[wc],0,0,0);
        }
      }
    } else {
      int d=tt;
      const unsigned short* A3b=A3+(size_t)bf*9*4096;
#pragma unroll
      for(int ti=0;ti<3;ti++){
        int lr=d*(ti-1)+3;
#pragma unroll
        for(int tj=0;tj<3;tj++){
          int tap=ti*3+tj;
          int dw=d*(tj-1)+3;
          const unsigned short* Ab=A3b+(size_t)tap*4096;
#pragma unroll
          for(int c0=0;c0<64;c0+=32){
            short8 a=*(const short8*)(Ab+((mt*16+n0)*64+c0+kg*8));
#pragma unroll
            for(int wc=0;wc<3;wc++){
              short8 bv=*(const short8*)(slab + (lr*54 + wc*16+n0+dw)*SLABP + c0+kg*8);
              acc[wc]=__builtin_amdgcn_mfma_f32_16x16x32_bf16(a,bv,acc[wc],0,0,0);
            }
          }
        }
      }
    }
#pragma unroll
    for(int wc=0;wc<3;wc++)
#pragma unroll
      for(int reg=0;reg<4;reg++)
        xsum[wc][reg]+=leaky((acc[wc][reg]-m_[reg])*scale[reg]+be_[reg]);
  }
#pragma unroll
  for(int wc=0;wc<3;wc++)
#pragma unroll
    for(int reg=0;reg<4;reg++)
      atomicAdd(&xl[(obase+reg)*50 + wc*16+n0], xsum[wc][reg]*0.125f);
  __syncthreads();
  size_t base=(size_t)b*64*HW + r0*48;
  for(int e=tid;e<3072;e+=512){
    int o=e/48, px=e-o*48;
    float s=zc_b[o];
#pragma unroll
    for(int c=0;c<64;c++) s+=zl[o*64+c]*xl[c*50+px];
    size_t a=base+(size_t)o*HW+px;
    out[a]=s+img[a];
  }
}

extern "C" void kernel_launch(void* const* d_in, const int* in_sizes, int n_in,
                              void* d_out, int out_size, void* d_ws, size_t ws_size,
                              hipStream_t stream){
  const float* bank   =(const float*)d_in[0];
  const float* task_f =(const float*)d_in[1];
  const float* img_f  =(const float*)d_in[2];
  const float* protos =(const float*)d_in[3];
  const float* tA_w1  =(const float*)d_in[4];
  const float* tA_w2  =(const float*)d_in[5];
  const float* iA_w   =(const float*)d_in[6];
  const float* iA_bn  =(const float*)d_in[7];
  const float* at_w1  =(const float*)d_in[8];
  const float* at_b1  =(const float*)d_in[9];
  const float* at_ln_g=(const float*)d_in[10];
  const float* at_ln_b=(const float*)d_in[11];
  const float* at_w2  =(const float*)d_in[12];
  const float* at_b2  =(const float*)d_in[13];
  const float* bv_t1  =(const float*)d_in[14];
  const float* bv_t2  =(const float*)d_in[15];
  const float* bv_ic1 =(const float*)d_in[16];
  const float* bv_bn1 =(const float*)d_in[17];
  const float* bv_ic2 =(const float*)d_in[18];
  const float* bv_bn2 =(const float*)d_in[19];
  const float* bv_w1  =(const float*)d_in[20];
  const float* bv_b1  =(const float*)d_in[21];
  const float* bv_ln_g=(const float*)d_in[22];
  const float* bv_ln_b=(const float*)d_in[23];
  const float* bv_w2  =(const float*)d_in[24];
  const float* bv_b2  =(const float*)d_in[25];
  const float* m1_w1  =(const float*)d_in[26];
  const float* m1_b1  =(const float*)d_in[27];
  const float* m1_ln_g=(const float*)d_in[28];
  const float* m1_ln_b=(const float*)d_in[29];
  const float* m1_w2  =(const float*)d_in[30];
  const float* m1_b2  =(const float*)d_in[31];
  const float* m3_w1  =(const float*)d_in[32];
  const float* m3_b1  =(const float*)d_in[33];
  const float* m3_ln_g=(const float*)d_in[34];
  const float* m3_ln_b=(const float*)d_in[35];
  const float* m3_w2  =(const float*)d_in[36];
  const float* m3_b2  =(const float*)d_in[37];
  const float* blr_bn =(const float*)d_in[38];
  const float* zc_w   =(const float*)d_in[39];
  const float* zc_b   =(const float*)d_in[40];

  float* ws=(float*)d_ws;
  float* totA=ws+0;       float* a0A=ws+16;      float* aLA=ws+32;
  float* totB=ws+48;      float* a0B=ws+304;     float* aLB=ws+560;
  float* rmsacc=ws+816;   float* i1 =ws+820;     float* ie =ws+852;   // ..1364
  int*   idxp  =(int*)(ws+2932);
  float* hid1=ws+3044;    float* hid3=ws+5092;
  unsigned short* A1p  =(unsigned short*)(ws+7140);     // 131072 bf16
  unsigned short* A3p  =(unsigned short*)(ws+72676);    // 1179648 bf16
  unsigned short* imgTP=(unsigned short*)(ws+662500);   // 746496 bf16 (padded)
  unsigned short* ie1TP=(unsigned short*)(ws+1035748);  // 746496 bf16 (padded)
  unsigned short* W1Tp =(unsigned short*)(ws+1408996);  // 36864 bf16
  unsigned short* W2Tp =(unsigned short*)(ws+1427428);  // 73728 bf16
  unsigned short* WATp =(unsigned short*)(ws+1464292);  // 9216 bf16 -> ends 1468900
  // total ~5.9 MB

  hipMemsetAsync(ws, 0, 1364*sizeof(float), stream);                 // stats accumulators
  hipMemsetAsync(imgTP, 0, 2*746496*sizeof(unsigned short), stream); // padded halos

  k_pre<<<868,256,0,stream>>>(task_f, tA_w1, bv_t1,
                              totA, a0A, aLA, totB, a0B, aLB, rmsacc,
                              img_f, bv_ic1, bv_ic2, iA_w, imgTP, W1Tp, W2Tp, WATp);
  k_conv1<<<120,256,0,stream>>>(imgTP, W1Tp, WATp, bv_bn1, iA_bn, ie1TP, i1);
  k_ic2M<<<dim3(96,2),256,0,stream>>>(ie1TP, W2Tp, bv_bn2, ie);
  k_mid<<<4,256,0,stream>>>(totA,a0A,aLA,totB,a0B,aLB, rmsacc, tA_w2, bv_t2, i1, ie,
                            at_w1, at_b1, at_ln_g, at_ln_b, at_w2, at_b2, protos,
                            bv_w1, bv_b1, bv_ln_g, bv_ln_b, bv_w2, bv_b2, bank,
                            m1_w1, m1_b1, m1_ln_g, m1_ln_b,
                            m3_w1, m3_b1, m3_ln_g, m3_ln_b,
                            idxp, hid1, hid3);
  k_heads<<<160,256,0,stream>>>(hid1, hid3, m1_w2, m1_b2, m3_w2, m3_b2, A1p, A3p);
  k_dynF<<<192,512,0,stream>>>(imgTP, A1p, A3p, idxp, blr_bn, zc_w, zc_b, img_f, (float*)d_out);

  (void)in_sizes; (void)n_in; (void)out_size; (void)ws_size;
}

// Round 12
// 286.993 us; speedup vs baseline: 1.2347x; 1.0173x over previous
//
#include <hip/hip_runtime.h>
#include <math.h>

#define LEAKC 0.2f

#define NB 4
#define NC 64
#define LLEN 16384
#define HW 2304
#define PP 54          // padded pitch (48 + 2*3)
#define PHW 2916       // 54*54

typedef __attribute__((ext_vector_type(8))) short short8;
typedef __attribute__((ext_vector_type(4))) float floatx4;

__device__ __forceinline__ float leaky(float x){ return x > 0.f ? x : LEAKC*x; }

__device__ __forceinline__ float wave_sum64(float v){
  for(int off=32;off;off>>=1) v += __shfl_xor(v,off);
  return v;
}

__device__ __forceinline__ unsigned short f2bf(float x){
  unsigned u=__float_as_uint(x);
  unsigned r=u+0x7FFFu+((u>>16)&1u);
  return (unsigned short)(r>>16);
}

__device__ __forceinline__ void threefry2x32(unsigned k0, unsigned k1, unsigned& x0, unsigned& x1){
  unsigned ks0=k0, ks1=k1, ks2=k0^k1^0x1BD11BDAu;
  x0+=ks0; x1+=ks1;
  const int rot0[4]={13,15,26,6};
  const int rot1[4]={17,29,16,24};
#define TF_APPLY(rr) {for(int r=0;r<4;r++){x0+=x1; x1=(x1<<rr[r])|(x1>>(32-rr[r])); x1^=x0;}}
  TF_APPLY(rot0); x0+=ks1; x1+=ks2+1u;
  TF_APPLY(rot1); x0+=ks2; x1+=ks0+2u;
  TF_APPLY(rot0); x0+=ks0; x1+=ks1+3u;
  TF_APPLY(rot1); x0+=ks1; x1+=ks2+4u;
  TF_APPLY(rot0); x0+=ks2; x1+=ks0+5u;
#undef TF_APPLY
}

__device__ __forceinline__ float jax_uniform128(int i){
  unsigned x0=0u, x1=(unsigned)i;
  threefry2x32(0u,42u,x0,x1);
  unsigned bits = x0 ^ x1;
  unsigned fb=(bits>>9)|0x3f800000u;
  float f=__uint_as_float(fb)-1.0f;
  float u=f*(1.0f-1e-10f)+1e-10f;
  return fmaxf(1e-10f,u);
}

// ---------------- k_pre: stats (0..255) + padded imgT (256..399) + weight prep (400..867) + L3 warm (868..883) ----------------
__global__ __launch_bounds__(256) void k_pre(const float* __restrict__ task_f,
                      const float* __restrict__ w1A, const float* __restrict__ w1B,
                      float* __restrict__ totA, float* __restrict__ a0A, float* __restrict__ aLA,
                      float* __restrict__ totB, float* __restrict__ a0B, float* __restrict__ aLB,
                      float* __restrict__ rmsacc,
                      const float* __restrict__ img,
                      const float* __restrict__ w1, const float* __restrict__ w2,
                      const float* __restrict__ wa,
                      unsigned short* __restrict__ imgTP,
                      unsigned short* __restrict__ W1T, unsigned short* __restrict__ W2T,
                      unsigned short* __restrict__ WAT,
                      const float* __restrict__ mw1, const float* __restrict__ mw3,
                      const float* __restrict__ bvw1p, const float* __restrict__ bvw2p,
                      const float* __restrict__ bvt2p, const float* __restrict__ atw2p,
                      const float* __restrict__ bankp, float* __restrict__ warm){
  if(blockIdx.x<256){
    int b=blockIdx.x>>6, seg=blockIdx.x&63;
    const float* x=task_f+b*LLEN;
    float tA[4]={0,0,0,0};
    float tB[64];
#pragma unroll
    for(int c=0;c<64;c++) tB[c]=0.f;
    float sq=0.f;
    int l=seg*256+threadIdx.x;
    {
      float xm=(l>0)?x[l-1]:0.f;
      float xc=x[l];
      float xp=(l<LLEN-1)?x[l+1]:0.f;
      sq=xc*xc;
#pragma unroll
      for(int c=0;c<4;c++){
        float a=leaky(w1A[c*3+0]*xm + w1A[c*3+1]*xc + w1A[c*3+2]*xp);
        tA[c]=a;
        if(l==0) a0A[b*4+c]=a;
        if(l==LLEN-1) aLA[b*4+c]=a;
      }
#pragma unroll
      for(int c=0;c<64;c++){
        float a=leaky(w1B[c*3+0]*xm + w1B[c*3+1]*xc + w1B[c*3+2]*xp);
        tB[c]=a;
        if(l==0) a0B[b*64+c]=a;
        if(l==LLEN-1) aLB[b*64+c]=a;
      }
    }
    sq=wave_sum64(sq);
#pragma unroll
    for(int c=0;c<4;c++) tA[c]=wave_sum64(tA[c]);
#pragma unroll
    for(int c=0;c<64;c++){
      float v=tB[c];
      for(int off=32;off;off>>=1) v+=__shfl_down(v,off);
      tB[c]=v;
    }
    __shared__ float redB[4][64];
    __shared__ float redA[4][4];
    __shared__ float redQ[4];
    int wave=threadIdx.x>>6, lane=threadIdx.x&63;
    if(lane==0){
#pragma unroll
      for(int c=0;c<64;c++) redB[wave][c]=tB[c];
#pragma unroll
      for(int c=0;c<4;c++) redA[wave][c]=tA[c];
      redQ[wave]=sq;
    }
    __syncthreads();
    if(threadIdx.x<64){
      float s=redB[0][threadIdx.x]+redB[1][threadIdx.x]+redB[2][threadIdx.x]+redB[3][threadIdx.x];
      atomicAdd(&totB[b*64+threadIdx.x], s);
    } else if(threadIdx.x<68){
      int c=threadIdx.x-64;
      float s=redA[0][c]+redA[1][c]+redA[2][c]+redA[3][c];
      atomicAdd(&totA[b*4+c], s);
    } else if(threadIdx.x==68){
      atomicAdd(&rmsacc[b], redQ[0]+redQ[1]+redQ[2]+redQ[3]);
    }
  } else if(blockIdx.x<400){
    int blk=blockIdx.x-256;
    int b=blk/36, t=blk%36;
    int p0=t*64;
    __shared__ float tile[64][65];
    int pp=threadIdx.x&63, c4=threadIdx.x>>6;
    for(int r=0;r<16;r++){
      int c=c4*16+r;
      tile[c][pp]=img[(b*64+c)*HW + p0+pp];
    }
    __syncthreads();
    int pxl=threadIdx.x>>2, cg=(threadIdx.x&3)*16;
    unsigned out[8];
#pragma unroll
    for(int q=0;q<8;q++){
      unsigned lo=f2bf(tile[cg+2*q][pxl]);
      unsigned hi=f2bf(tile[cg+2*q+1][pxl]);
      out[q]=lo|(hi<<16);
    }
    int px=p0+pxl;
    int h=px/48, w=px-h*48;
    int poff=(h+3)*PP+(w+3);
    unsigned* dst=(unsigned*)(imgTP + ((size_t)(b*PHW+poff))*64 + cg);
#pragma unroll
    for(int q=0;q<8;q++) dst[q]=out[q];
  } else if(blockIdx.x<868){
    int n=(blockIdx.x-400)*256+threadIdx.x;
    if(n<9*64*64){
      int tap=n>>12, oc=(n>>6)&63, c=n&63;
      W1T[n]=f2bf(w1[oc*576+c*9+tap]);
    } else if(n<9*64*64+9*128*64){
      int m=n-9*64*64;
      int tap=m/8192, r=m-tap*8192, oc=r>>6, c=r&63;
      W2T[m]=f2bf(w2[oc*576+c*9+tap]);
    } else {
      int q=n-9*64*64-9*128*64;
      if(q<9*16*64){
        int tap=q>>10, r=q&1023, o=r>>6, c=r&63;
        WAT[q]=(o<8)?f2bf(wa[o*576+c*9+tap]):(unsigned short)0;
      }
    }
  } else {
    // L3 warm of k_mid's weight set (touch every 64B line)
    int t=(blockIdx.x-868)*256+threadIdx.x;   // 0..4095
    float a=0.f;
    for(int i=t;i*16<16384;i+=4096) a+=mw1[i*16];
    for(int i=t;i*16<16384;i+=4096) a+=mw3[i*16];
    for(int i=t;i*16<16384;i+=4096) a+=bvw1p[i*16];
    for(int i=t;i*16<16384;i+=4096) a+=bvw2p[i*16];
    for(int i=t;i*16<24576;i+=4096) a+=bvt2p[i*16];
    for(int i=t;i*16<8192;i+=4096) a+=atw2p[i*16];
    for(int i=t;i*16<16384;i+=4096) a+=bankp[i*16];
    warm[t&1023]=a;   // dummy sink, never read
  }
}

// ---------------- k_conv1: ic1 MFMA (0..95, two rows/block) + iA MFMA mean (96..119) ----------------
__global__ __launch_bounds__(256) void k_conv1(const unsigned short* __restrict__ imgTP,
                        const unsigned short* __restrict__ W1T,
                        const unsigned short* __restrict__ WAT,
                        const float* __restrict__ bn1, const float* __restrict__ bnA,
                        unsigned short* __restrict__ ie1TP, float* __restrict__ i1){
  int lane=threadIdx.x&63, mt=threadIdx.x>>6;
  int n0=lane&15, kg=lane>>4;
  if(blockIdx.x<96){
    int blk=blockIdx.x;
    int b=blk/24, hp=blk-b*24;
    int h0=hp*2;
    const unsigned short* ib=imgTP+(size_t)b*PHW*64;
    floatx4 acc[6];
#pragma unroll
    for(int i=0;i<6;i++) acc[i]=(floatx4){0.f,0.f,0.f,0.f};
#pragma unroll
    for(int ti=0;ti<3;ti++){
#pragma unroll
      for(int tj=0;tj<3;tj++){
        int tap=ti*3+tj;
        const unsigned short* Ab=W1T+(size_t)tap*4096;
#pragma unroll
        for(int c0=0;c0<64;c0+=32){
          short8 a=*(const short8*)(Ab+((mt*16+n0)*64+c0+kg*8));
#pragma unroll
          for(int rr=0;rr<2;rr++){
            int r=h0+rr+ti-1+3;
#pragma unroll
            for(int wc=0;wc<3;wc++){
              int w=wc*16+n0+tj-1+3;
              short8 bv=*(const short8*)(ib+((size_t)(r*PP+w)*64+c0+kg*8));
              acc[rr*3+wc]=__builtin_amdgcn_mfma_f32_16x16x32_bf16(a,bv,acc[rr*3+wc],0,0,0);
            }
          }
        }
      }
    }
    int obase=mt*16+kg*4;
    float scale[4],m_[4],be_[4];
#pragma unroll
    for(int reg=0;reg<4;reg++){
      int o=obase+reg;
      scale[reg]=bn1[o]/sqrtf(bn1[192+o]+1e-5f);
      m_[reg]=bn1[128+o]; be_[reg]=bn1[64+o];
    }
#pragma unroll
    for(int rr=0;rr<2;rr++){
#pragma unroll
      for(int wc=0;wc<3;wc++){
        int poff=(h0+rr+3)*PP + wc*16+n0+3;
        float v0=leaky((acc[rr*3+wc][0]-m_[0])*scale[0]+be_[0]);
        float v1=leaky((acc[rr*3+wc][1]-m_[1])*scale[1]+be_[1]);
        float v2=leaky((acc[rr*3+wc][2]-m_[2])*scale[2]+be_[2]);
        float v3=leaky((acc[rr*3+wc][3]-m_[3])*scale[3]+be_[3]);
        unsigned w0=f2bf(v0)|((unsigned)f2bf(v1)<<16);
        unsigned w1=f2bf(v2)|((unsigned)f2bf(v3)<<16);
        uint2 pk={w0,w1};
        *(uint2*)(ie1TP+((size_t)(b*PHW+poff)*64+obase))=pk;
      }
    }
  } else {
    int blk=blockIdx.x-96;
    int b=blk/6, hg=blk%6;
    int hp=hg*4+mt;
    int h0=hp*2;
    const unsigned short* ib=imgTP+(size_t)b*PHW*64;
    floatx4 acc[6];
#pragma unroll
    for(int i=0;i<6;i++) acc[i]=(floatx4){0.f,0.f,0.f,0.f};
#pragma unroll
    for(int ti=0;ti<3;ti++){
#pragma unroll
      for(int tj=0;tj<3;tj++){
        int tap=ti*3+tj;
        const unsigned short* Ab=WAT+(size_t)tap*1024;
#pragma unroll
        for(int c0=0;c0<64;c0+=32){
          short8 a=*(const short8*)(Ab+(n0*64+c0+kg*8));
#pragma unroll
          for(int rr=0;rr<2;rr++){
            int r=h0+rr+ti-1+3;
#pragma unroll
            for(int wc=0;wc<3;wc++){
              int w=wc*16+n0+tj-1+3;
              short8 bv=*(const short8*)(ib+((size_t)(r*PP+w)*64+c0+kg*8));
              acc[rr*3+wc]=__builtin_amdgcn_mfma_f32_16x16x32_bf16(a,bv,acc[rr*3+wc],0,0,0);
            }
          }
        }
      }
    }
    int obase=kg*4;
#pragma unroll
    for(int reg=0;reg<4;reg++){
      int o=obase+reg;
      float part=0;
      if(o<8){
        float scale=bnA[o]/sqrtf(bnA[24+o]+1e-5f);
        float m_=bnA[16+o], be_=bnA[8+o];
#pragma unroll
        for(int i=0;i<6;i++) part+=leaky((acc[i][reg]-m_)*scale+be_);
      }
      for(int off=1;off<16;off<<=1) part+=__shfl_xor(part,off);
      if(n0==0 && o<8) atomicAdd(&i1[b*8+o], part*(1.f/2304.f));
    }
  }
}

// ---------------- bv_ic2 conv via MFMA + mean, branchless via padded input ----------------
__global__ __launch_bounds__(256) void k_ic2M(const unsigned short* __restrict__ ie1TP,
                       const unsigned short* __restrict__ W2T,
                       const float* __restrict__ bn, float* __restrict__ ie){
  int blk=blockIdx.x;
  int b=blk/24, hp=blk-b*24;
  int mo=blockIdx.y*64;
  int lane=threadIdx.x&63, mt=threadIdx.x>>6;
  int n0=lane&15, kg=lane>>4;
  int h0=hp*2;
  const unsigned short* ib=ie1TP+(size_t)b*PHW*64;
  floatx4 acc[6];
#pragma unroll
  for(int i=0;i<6;i++) acc[i]=(floatx4){0.f,0.f,0.f,0.f};
#pragma unroll
  for(int ti=0;ti<3;ti++){
#pragma unroll
    for(int tj=0;tj<3;tj++){
      int tap=ti*3+tj;
      const unsigned short* Ab=W2T+(size_t)tap*8192;
#pragma unroll
      for(int c0=0;c0<64;c0+=32){
        short8 a=*(const short8*)(Ab+((mo+mt*16+n0)*64+c0+kg*8));
#pragma unroll
        for(int rr=0;rr<2;rr++){
          int r=h0+rr+ti-1+3;
#pragma unroll
          for(int wc=0;wc<3;wc++){
            int w=wc*16+n0+tj-1+3;
            short8 bv=*(const short8*)(ib+((size_t)(r*PP+w)*64+c0+kg*8));
            acc[rr*3+wc]=__builtin_amdgcn_mfma_f32_16x16x32_bf16(a,bv,acc[rr*3+wc],0,0,0);
          }
        }
      }
    }
  }
  int obase=mo+mt*16+kg*4;
#pragma unroll
  for(int reg=0;reg<4;reg++){
    int o=obase+reg;
    float scale=bn[o]/sqrtf(bn[384+o]+1e-5f);
    float m_=bn[256+o], be_=bn[128+o];
    float part=0;
#pragma unroll
    for(int i=0;i<6;i++) part+=leaky((acc[i][reg]-m_)*scale+be_);
    for(int off=1;off<16;off<<=1) part+=__shfl_xor(part,off);
    if(n0==0) atomicAdd(&ie[b*128+o], part*(1.f/2304.f));
  }
}

// ---------------- fused mid, PER-BATCH block (grid=4, 512 threads, K-split stages) ----------------
__global__ __launch_bounds__(512,1) void k_mid(
    const float* __restrict__ totA, const float* __restrict__ a0A, const float* __restrict__ aLA,
    const float* __restrict__ totB, const float* __restrict__ a0B, const float* __restrict__ aLB,
    const float* __restrict__ rmsacc,
    const float* __restrict__ tA_w2, const float* __restrict__ bv_t2,
    const float* __restrict__ i1, const float* __restrict__ ie,
    const float* __restrict__ at_w1, const float* __restrict__ at_b1,
    const float* __restrict__ at_ln_g, const float* __restrict__ at_ln_b,
    const float* __restrict__ at_w2, const float* __restrict__ at_b2,
    const float* __restrict__ protos,
    const float* __restrict__ bv_w1, const float* __restrict__ bv_b1,
    const float* __restrict__ bv_ln_g, const float* __restrict__ bv_ln_b,
    const float* __restrict__ bv_w2, const float* __restrict__ bv_b2,
    const float* __restrict__ bank,
    const float* __restrict__ m1_w1, const float* __restrict__ m1_b1,
    const float* __restrict__ m1_g,  const float* __restrict__ m1_bb,
    const float* __restrict__ m3_w1, const float* __restrict__ m3_b1,
    const float* __restrict__ m3_g,  const float* __restrict__ m3_bb,
    int* __restrict__ idxo, float* __restrict__ hid1, float* __restrict__ hid3){
  int b=blockIdx.x;
  int tid=threadIdx.x;
  int lane=tid&63, wv=tid>>6;
  const float invL=1.0f/16384.0f;
  __shared__ float sT[64], s0[64], sL[64];
  __shared__ float part[512];
  __shared__ float te_s[128], t1_s[8];
  __shared__ float f1[16], h[64], tif[128], tifn[128], tden[8], pden[4], pn[64], z[32];
  __shared__ int sidx[8], sfirst[4], srank[8], rows[8];
  __shared__ float fbuf[256], hh[64], ffn_s[256], finv_s;
  __shared__ float scores[64];
  __shared__ int order[64];
  __shared__ float bvf[2048];

  if(tid<64){ sT[tid]=totB[b*64+tid]; s0[tid]=a0B[b*64+tid]; sL[tid]=aLB[b*64+tid]; }
  __syncthreads();
  float scB=1.0f/(sqrtf(rmsacc[b]*invL)+1e-8f);
  // ---- te: K-split 2-way over c1 halves ----
  if(tid<256){
    int c2=tid&127, h2=tid>>7;
    const float* wr=bv_t2+c2*192;
    float s=0;
    for(int c1=h2*32;c1<h2*32+32;c1+=8){
      float4 q[6];
      const float4* r4=(const float4*)(wr+c1*3);
#pragma unroll
      for(int u=0;u<6;u++) q[u]=r4[u];
      const float* qq=(const float*)q;
#pragma unroll
      for(int u=0;u<8;u++){
        int c=c1+u;
        float T=sT[c], A0=s0[c], AL=sL[c];
        s += qq[u*3+0]*(T-AL) + qq[u*3+1]*T + qq[u*3+2]*(T-A0);
      }
    }
    part[tid]=s;
  } else if(tid>=384 && tid<392){
    int c2=tid-384;
    float s=0;
    for(int c1=0;c1<4;c1++){
      float T=totA[b*4+c1], A0=a0A[b*4+c1], AL=aLA[b*4+c1];
      const float* w=&tA_w2[(c2*4+c1)*3];
      s += w[0]*(T-AL) + w[1]*T + w[2]*(T-A0);
    }
    t1_s[c2]=s*invL;
  }
  __syncthreads();
  if(tid<128) te_s[tid]=(part[tid]+part[tid+128])*invL*scB;
  __syncthreads();

  // ---- attention MLP ----
  if(tid<8) f1[tid]=t1_s[tid];
  else if(tid<16) f1[tid]=i1[b*8+tid-8];
  __syncthreads();
  if(tid<64){
    float s=at_b1[lane];
#pragma unroll
    for(int i=0;i<16;i++) s+=f1[i]*at_w1[i*64+lane];
    float mu=wave_sum64(s)*(1.f/64.f);
    float d=s-mu;
    float var=wave_sum64(d*d)*(1.f/64.f);
    h[lane]=fmaxf(d*(1.0f/sqrtf(var+1e-5f))*at_ln_g[lane]+at_ln_b[lane],0.f);
  }
  __syncthreads();
  if(tid<256){
    int n=tid&127, h2=tid>>7;
    float a0=0,a1=0;
    for(int k=h2*32;k<h2*32+32;k+=2){
      a0+=h[k]*at_w2[k*128+n];
      a1+=h[k+1]*at_w2[(k+1)*128+n];
    }
    part[tid]=a0+a1;
  }
  __syncthreads();
  if(tid<128) tif[tid]=at_b2[tid]+part[tid]+part[tid+128];
  __syncthreads();
  if(tid<8){
    int f=tid;
    float ss=0; for(int e=0;e<16;e++){float v=tif[e*8+f]; ss+=v*v;}
    tden[f]=fmaxf(sqrtf(ss),1e-8f);
  } else if(tid<12){
    int t=tid-8;
    float ss=0; for(int e=0;e<16;e++){float v=protos[t*16+e]; ss+=v*v;}
    pden[t]=fmaxf(sqrtf(ss),1e-8f);
  }
  __syncthreads();
  if(tid<128) tifn[tid]=tif[tid]/tden[tid&7];
  if(tid<64) pn[tid]=protos[tid]/pden[tid>>4];
  __syncthreads();
  if(tid<32){
    int f=tid>>2, t=tid&3;
    float ss=0;
#pragma unroll
    for(int e=0;e<16;e++) ss+=pn[t*16+e]*tifn[e*8+f];
    float u=jax_uniform128(b*32+f*4+t);
    float g=-logf(-logf(u));
    z[tid]=ss+g;
  }
  __syncthreads();
  if(tid<8){
    float best=z[tid*4]; int bi=0;
    for(int t=1;t<4;t++){ float v=z[tid*4+t]; if(v>best){best=v;bi=t;} }
    sidx[tid]=bi;
  }
  __syncthreads();
  if(tid<4){
    int t=tid;
    int fi=0;
    for(int f=7;f>=0;f--) if(sidx[f]==t) fi=f;
    sfirst[t]=fi;
  } else if(tid<12){
    int f=tid-4;
    int c=0; for(int f2=0;f2<f;f2++) if(sidx[f2]==sidx[f]) c++;
    srank[f]=c;
  }
  __syncthreads();

  // ---- branch-B MLP: bv_w1 (K-split 4-way) ----
  if(tid<128) fbuf[tid]=te_s[tid];
  else if(tid<256) fbuf[tid]=ie[b*128+tid-128];
  __syncthreads();
  if(tid<256){
    int l64=tid&63, q=tid>>6;
    float a0=0,a1=0,a2=0,a3=0;
    for(int k=q*64;k<q*64+64;k+=4){
      a0+=fbuf[k]  *bv_w1[k*64+l64];
      a1+=fbuf[k+1]*bv_w1[(k+1)*64+l64];
      a2+=fbuf[k+2]*bv_w1[(k+2)*64+l64];
      a3+=fbuf[k+3]*bv_w1[(k+3)*64+l64];
    }
    part[tid]=((a0+a1)+(a2+a3));
  }
  __syncthreads();
  if(tid<64){
    float s=bv_b1[lane]+part[lane]+part[64+lane]+part[128+lane]+part[192+lane];
    float mu=wave_sum64(s)*(1.f/64.f);
    float d=s-mu;
    float var=wave_sum64(d*d)*(1.f/64.f);
    hh[lane]=fmaxf(d*(1.0f/sqrtf(var+1e-5f))*bv_ln_g[lane]+bv_ln_b[lane],0.f);
  }
  __syncthreads();
  // ---- bv_w2 (K-split 2-way, all 512 threads) ----
  {
    int n=tid&255, h2=tid>>8;
    float a0=0,a1=0;
    for(int k=h2*32;k<h2*32+32;k+=2){
      a0+=hh[k]*bv_w2[k*256+n];
      a1+=hh[k+1]*bv_w2[(k+1)*256+n];
    }
    part[tid]=a0+a1;
  }
  __syncthreads();
  if(tid<256) ffn_s[tid]=bv_b2[tid]+part[tid]+part[tid+256];
  __syncthreads();
  if(tid<64){
    float sq=0;
#pragma unroll
    for(int u=0;u<4;u++){ float v=ffn_s[u*64+lane]; sq+=v*v; }
    sq=wave_sum64(sq);
    if(lane==0) finv_s=1.0f/fmaxf(sqrtf(sq),1e-12f);
  }
  __syncthreads();
  if(tid<256) ffn_s[tid]*=finv_s;
  __syncthreads();

  // ---- scores (K-split 2-way) ----
  if(tid<128){
    int it=tid&63, h2=tid>>6;
    int t=it>>4, v=it&15;
    int tt=sidx[sfirst[t]];
    const float4* row=(const float4*)(bank+(tt*16+v)*256);
    float sa=0,na=0;
    for(int d4=h2*32;d4<h2*32+32;d4++){
      float4 r=row[d4];
      const float* fp=&ffn_s[d4*4];
      sa+=fp[0]*r.x+fp[1]*r.y+fp[2]*r.z+fp[3]*r.w;
      na+=r.x*r.x+r.y*r.y+r.z*r.z+r.w*r.w;
    }
    part[tid]=sa;
    part[256+tid]=na;
  }
  __syncthreads();
  if(tid<64) scores[tid]=(part[tid]+part[tid+64])/fmaxf(sqrtf(part[256+tid]+part[320+tid]),1e-12f);
  __syncthreads();
  if(tid<4){
    const float* sc=&scores[tid*16];
    unsigned used=0;
    for(int pk=0;pk<16;pk++){
      int best=-1; float bv=-1e30f;
      for(int v2=0;v2<16;v2++){
        if(used&(1u<<v2)) continue;
        float vv=sc[v2];
        if(best<0||vv>bv){bv=vv;best=v2;}
      }
      used|=1u<<best;
      order[tid*16+pk]=best;
    }
  }
  __syncthreads();
  if(tid<8){
    int t=sidx[tid];
    int v=order[t*16+srank[tid]];
    rows[tid]=t*16+v;
    idxo[b*8+tid]=t;
  }
  __syncthreads();

  // ---- gather bank rows + m1/m3 hidden: one row per wave (8 waves) ----
  for(int ii=tid;ii<2048;ii+=512){
    int r=ii>>8, d=ii&255;
    bvf[ii]=bank[rows[r]*256+d];
  }
  __syncthreads();
  {
    int r=wv;
    const float* bp=&bvf[r*256];
    float a0=0,a1=0,a2=0,a3=0;
    float c0=0,c1=0,c2=0,c3=0;
    for(int d=0;d<256;d+=4){
      float b0=bp[d],b1=bp[d+1],b2=bp[d+2],b3=bp[d+3];
      a0+=b0*m1_w1[d*64+lane];
      a1+=b1*m1_w1[(d+1)*64+lane];
      a2+=b2*m1_w1[(d+2)*64+lane];
      a3+=b3*m1_w1[(d+3)*64+lane];
      c0+=b0*m3_w1[d*64+lane];
      c1+=b1*m3_w1[(d+1)*64+lane];
      c2+=b2*m3_w1[(d+2)*64+lane];
      c3+=b3*m3_w1[(d+3)*64+lane];
    }
    float s1=m1_b1[lane]+((a0+a1)+(a2+a3));
    float s3=m3_b1[lane]+((c0+c1)+(c2+c3));
    float mu=wave_sum64(s1)*(1.f/64.f);
    float dd=s1-mu;
    float var=wave_sum64(dd*dd)*(1.f/64.f);
    hid1[(b*8+r)*64+lane]=fmaxf(dd*(1.0f/sqrtf(var+1e-5f))*m1_g[lane]+m1_bb[lane],0.f);
    mu=wave_sum64(s3)*(1.f/64.f);
    dd=s3-mu;
    var=wave_sum64(dd*dd)*(1.f/64.f);
    hid3[(b*8+r)*64+lane]=fmaxf(dd*(1.0f/sqrtf(var+1e-5f))*m3_g[lane]+m3_bb[lane],0.f);
  }
}

// ---------------- k_heads ----------------
__global__ __launch_bounds__(256) void k_heads(const float* __restrict__ hid1, const float* __restrict__ hid3,
                        const float* __restrict__ w2a, const float* __restrict__ b2a,
                        const float* __restrict__ w2b, const float* __restrict__ b2b,
                        unsigned short* __restrict__ A1, unsigned short* __restrict__ A3){
  __shared__ float hl[2048];
  if(blockIdx.x<16){
    int n=blockIdx.x*256+threadIdx.x;
    for(int i=threadIdx.x;i<2048;i+=256) hl[i]=hid1[i];
    __syncthreads();
    float wcol[64];
#pragma unroll
    for(int k=0;k<64;k++) wcol[k]=w2a[k*4096+n];
    float bb=b2a[n];
    for(int bf=0;bf<32;bf++){
      float s=bb;
#pragma unroll
      for(int k=0;k<64;k++) s+=hl[bf*64+k]*wcol[k];
      A1[bf*4096+n]=f2bf(s);
    }
  } else {
    int n=(blockIdx.x-16)*256+threadIdx.x;
    for(int i=threadIdx.x;i<2048;i+=256) hl[i]=hid3[i];
    __syncthreads();
    float wcol[64];
#pragma unroll
    for(int k=0;k<64;k++) wcol[k]=w2b[(size_t)k*36864+n];
    float bb=b2b[n];
    int o=n/576, rem=n-o*576;
    int c=rem/9, tap=rem-c*9;
    size_t base=((size_t)tap*64+o)*64+c;
    for(int bf=0;bf<32;bf++){
      float s=bb;
#pragma unroll
      for(int k=0;k<64;k++) s+=hl[bf*64+k]*wcol[k];
      A3[(size_t)bf*9*4096+base]=f2bf(s);
    }
  }
}

// ---------------- fused dynamic conv: LDS-staged image slab, 512 thr, f-halves, zc+residual ----------------
#define SLABP 72   // c-pitch in slab (64 + 8) -> rotates banks, 2-way max
__global__ __launch_bounds__(512) void k_dynF(const unsigned short* __restrict__ imgTP,
                       const unsigned short* __restrict__ A1, const unsigned short* __restrict__ A3,
                       const int* __restrict__ idx, const float* __restrict__ bn,
                       const float* __restrict__ zc_w, const float* __restrict__ zc_b,
                       const float* __restrict__ img, float* __restrict__ out){
  int blk=blockIdx.x;
  int b=blk/48, r0=blk-b*48;
  int tid=threadIdx.x;
  int lane=tid&63, w8=tid>>6;
  int mt=w8&3, fh=w8>>2;
  int n0=lane&15, kg=lane>>4;
  __shared__ unsigned short slab[7*54*SLABP];
  __shared__ float xl[64*50];
  __shared__ float zl[4096];
  for(int i=tid;i<4096;i+=512) zl[i]=zc_w[i];
  for(int i=tid;i<3200;i+=512) xl[i]=0.f;
  {
    const unsigned short* ibase=imgTP+((size_t)b*PHW+(size_t)r0*PP)*64;
    for(int e=tid;e<7*54*8;e+=512){
      int rr=e/(54*8), rem=e-rr*54*8, w=rem>>3, ck=rem&7;
      uint4 v=*(const uint4*)(ibase + ((size_t)(rr*PP+w))*64 + ck*8);
      *(uint4*)(slab + (rr*54+w)*SLABP + ck*8)=v;
    }
  }
  __syncthreads();
  int obase=mt*16+kg*4;
  float scale[4],m_[4],be_[4];
#pragma unroll
  for(int reg=0;reg<4;reg++){
    int o=obase+reg;
    scale[reg]=bn[o]/sqrtf(bn[192+o]+1e-5f);
    m_[reg]=bn[128+o]; be_[reg]=bn[64+o];
  }
  float xsum[3][4];
#pragma unroll
  for(int wc=0;wc<3;wc++)
#pragma unroll
    for(int reg=0;reg<4;reg++) xsum[wc][reg]=0.f;
  for(int f=fh*4;f<fh*4+4;f++){
    int bf=b*8+f;
    int tt=idx[bf];
    floatx4 acc[3];
#pragma unroll
    for(int i=0;i<3;i++) acc[i]=(floatx4){0.f,0.f,0.f,0.f};
    if(tt==0){
      const unsigned short* Ab=A1+(size_t)bf*4096;
#pragma unroll
      for(int c0=0;c0<64;c0+=32){
        short8 a=*(const short8*)(Ab+((mt*16+n0)*64+c0+kg*8));
#pragma unroll
        for(int wc=0;wc<3;wc++){
          short8 bv=*(const short8*)(slab + (3*54 + wc*16+n0+3)*SLABP + c0+kg*8);
          acc[wc]=__builtin_amdgcn_mfma_f32_16x16x32_bf16(a,bv,acc[wc],0,0,0);
        }
      }
    } else {
      int d=tt;
      const unsigned short* A3b=A3+(size_t)bf*9*4096;
#pragma unroll
      for(int ti=0;ti<3;ti++){
        int lr=d*(ti-1)+3;
#pragma unroll
        for(int tj=0;tj<3;tj++){
          int tap=ti*3+tj;
          int dw=d*(tj-1)+3;
          const unsigned short* Ab=A3b+(size_t)tap*4096;
#pragma unroll
          for(int c0=0;c0<64;c0+=32){
            short8 a=*(const short8*)(Ab+((mt*16+n0)*64+c0+kg*8));
#pragma unroll
            for(int wc=0;wc<3;wc++){
              short8 bv=*(const short8*)(slab + (lr*54 + wc*16+n0+dw)*SLABP + c0+kg*8);
              acc[wc]=__builtin_amdgcn_mfma_f32_16x16x32_bf16(a,bv,acc[wc],0,0,0);
            }
          }
        }
      }
    }
#pragma unroll
    for(int wc=0;wc<3;wc++)
#pragma unroll
      for(int reg=0;reg<4;reg++)
        xsum[wc][reg]+=leaky((acc[wc][reg]-m_[reg])*scale[reg]+be_[reg]);
  }
#pragma unroll
  for(int wc=0;wc<3;wc++)
#pragma unroll
    for(int reg=0;reg<4;reg++)
      atomicAdd(&xl[(obase+reg)*50 + wc*16+n0], xsum[wc][reg]*0.125f);
  __syncthreads();
  size_t base=(size_t)b*64*HW + r0*48;
  for(int e=tid;e<3072;e+=512){
    int o=e/48, px=e-o*48;
    float s=zc_b[o];
#pragma unroll
    for(int c=0;c<64;c++) s+=zl[o*64+c]*xl[c*50+px];
    size_t a=base+(size_t)o*HW+px;
    out[a]=s+img[a];
  }
}

extern "C" void kernel_launch(void* const* d_in, const int* in_sizes, int n_in,
                              void* d_out, int out_size, void* d_ws, size_t ws_size,
                              hipStream_t stream){
  const float* bank   =(const float*)d_in[0];
  const float* task_f =(const float*)d_in[1];
  const float* img_f  =(const float*)d_in[2];
  const float* protos =(const float*)d_in[3];
  const float* tA_w1  =(const float*)d_in[4];
  const float* tA_w2  =(const float*)d_in[5];
  const float* iA_w   =(const float*)d_in[6];
  const float* iA_bn  =(const float*)d_in[7];
  const float* at_w1  =(const float*)d_in[8];
  const float* at_b1  =(const float*)d_in[9];
  const float* at_ln_g=(const float*)d_in[10];
  const float* at_ln_b=(const float*)d_in[11];
  const float* at_w2  =(const float*)d_in[12];
  const float* at_b2  =(const float*)d_in[13];
  const float* bv_t1  =(const float*)d_in[14];
  const float* bv_t2  =(const float*)d_in[15];
  const float* bv_ic1 =(const float*)d_in[16];
  const float* bv_bn1 =(const float*)d_in[17];
  const float* bv_ic2 =(const float*)d_in[18];
  const float* bv_bn2 =(const float*)d_in[19];
  const float* bv_w1  =(const float*)d_in[20];
  const float* bv_b1  =(const float*)d_in[21];
  const float* bv_ln_g=(const float*)d_in[22];
  const float* bv_ln_b=(const float*)d_in[23];
  const float* bv_w2  =(const float*)d_in[24];
  const float* bv_b2  =(const float*)d_in[25];
  const float* m1_w1  =(const float*)d_in[26];
  const float* m1_b1  =(const float*)d_in[27];
  const float* m1_ln_g=(const float*)d_in[28];
  const float* m1_ln_b=(const float*)d_in[29];
  const float* m1_w2  =(const float*)d_in[30];
  const float* m1_b2  =(const float*)d_in[31];
  const float* m3_w1  =(const float*)d_in[32];
  const float* m3_b1  =(const float*)d_in[33];
  const float* m3_ln_g=(const float*)d_in[34];
  const float* m3_ln_b=(const float*)d_in[35];
  const float* m3_w2  =(const float*)d_in[36];
  const float* m3_b2  =(const float*)d_in[37];
  const float* blr_bn =(const float*)d_in[38];
  const float* zc_w   =(const float*)d_in[39];
  const float* zc_b   =(const float*)d_in[40];

  float* ws=(float*)d_ws;
  float* totA=ws+0;       float* a0A=ws+16;      float* aLA=ws+32;
  float* totB=ws+48;      float* a0B=ws+304;     float* aLB=ws+560;
  float* rmsacc=ws+816;   float* i1 =ws+820;     float* ie =ws+852;   // ..1364
  int*   idxp  =(int*)(ws+2932);
  float* hid1=ws+3044;    float* hid3=ws+5092;
  unsigned short* A1p  =(unsigned short*)(ws+7140);     // 131072 bf16
  unsigned short* A3p  =(unsigned short*)(ws+72676);    // 1179648 bf16
  unsigned short* imgTP=(unsigned short*)(ws+662500);   // 746496 bf16 (padded)
  unsigned short* ie1TP=(unsigned short*)(ws+1035748);  // 746496 bf16 (padded)
  unsigned short* W1Tp =(unsigned short*)(ws+1408996);  // 36864 bf16
  unsigned short* W2Tp =(unsigned short*)(ws+1427428);  // 73728 bf16
  unsigned short* WATp =(unsigned short*)(ws+1464292);  // 9216 bf16 -> ends 1468900
  float* warm =ws+1468900;                              // 1024 f dummy sink
  // total ~5.9 MB

  hipMemsetAsync(ws, 0, 1364*sizeof(float), stream);                 // stats accumulators
  hipMemsetAsync(imgTP, 0, 2*746496*sizeof(unsigned short), stream); // padded halos

  k_pre<<<884,256,0,stream>>>(task_f, tA_w1, bv_t1,
                              totA, a0A, aLA, totB, a0B, aLB, rmsacc,
                              img_f, bv_ic1, bv_ic2, iA_w, imgTP, W1Tp, W2Tp, WATp,
                              m1_w1, m3_w1, bv_w1, bv_w2, bv_t2, at_w2, bank, warm);
  k_conv1<<<120,256,0,stream>>>(imgTP, W1Tp, WATp, bv_bn1, iA_bn, ie1TP, i1);
  k_ic2M<<<dim3(96,2),256,0,stream>>>(ie1TP, W2Tp, bv_bn2, ie);
  k_mid<<<4,512,0,stream>>>(totA,a0A,aLA,totB,a0B,aLB, rmsacc, tA_w2, bv_t2, i1, ie,
                            at_w1, at_b1, at_ln_g, at_ln_b, at_w2, at_b2, protos,
                            bv_w1, bv_b1, bv_ln_g, bv_ln_b, bv_w2, bv_b2, bank,
                            m1_w1, m1_b1, m1_ln_g, m1_ln_b,
                            m3_w1, m3_b1, m3_ln_g, m3_ln_b,
                            idxp, hid1, hid3);
  k_heads<<<160,256,0,stream>>>(hid1, hid3, m1_w2, m1_b2, m3_w2, m3_b2, A1p, A3p);
  k_dynF<<<192,512,0,stream>>>(imgTP, A1p, A3p, idxp, blr_bn, zc_w, zc_b, img_f, (float*)d_out);

  (void)in_sizes; (void)n_in; (void)out_size; (void)ws_size;
}

// Round 13
// 275.813 us; speedup vs baseline: 1.2848x; 1.0405x over previous
//
#include <hip/hip_runtime.h>
#include <math.h>

#define LEAKC 0.2f

#define NB 4
#define NC 64
#define LLEN 16384
#define HW 2304
#define PP 54          // padded pitch (48 + 2*3)
#define PHW 2916       // 54*54
#define SLABP 72       // slab c-pitch: 2-way max conflicts (free per m136)

typedef __attribute__((ext_vector_type(8))) short short8;
typedef __attribute__((ext_vector_type(4))) float floatx4;

__device__ __forceinline__ float leaky(float x){ return x > 0.f ? x : LEAKC*x; }

__device__ __forceinline__ float wave_sum64(float v){
  for(int off=32;off;off>>=1) v += __shfl_xor(v,off);
  return v;
}

__device__ __forceinline__ unsigned short f2bf(float x){
  unsigned u=__float_as_uint(x);
  unsigned r=u+0x7FFFu+((u>>16)&1u);
  return (unsigned short)(r>>16);
}

__device__ __forceinline__ void threefry2x32(unsigned k0, unsigned k1, unsigned& x0, unsigned& x1){
  unsigned ks0=k0, ks1=k1, ks2=k0^k1^0x1BD11BDAu;
  x0+=ks0; x1+=ks1;
  const int rot0[4]={13,15,26,6};
  const int rot1[4]={17,29,16,24};
#define TF_APPLY(rr) {for(int r=0;r<4;r++){x0+=x1; x1=(x1<<rr[r])|(x1>>(32-rr[r])); x1^=x0;}}
  TF_APPLY(rot0); x0+=ks1; x1+=ks2+1u;
  TF_APPLY(rot1); x0+=ks2; x1+=ks0+2u;
  TF_APPLY(rot0); x0+=ks0; x1+=ks1+3u;
  TF_APPLY(rot1); x0+=ks1; x1+=ks2+4u;
  TF_APPLY(rot0); x0+=ks2; x1+=ks0+5u;
#undef TF_APPLY
}

__device__ __forceinline__ float jax_uniform128(int i){
  unsigned x0=0u, x1=(unsigned)i;
  threefry2x32(0u,42u,x0,x1);
  unsigned bits = x0 ^ x1;
  unsigned fb=(bits>>9)|0x3f800000u;
  float f=__uint_as_float(fb)-1.0f;
  float u=f*(1.0f-1e-10f)+1e-10f;
  return fmaxf(1e-10f,u);
}

// ---------------- k_pre: stats (0..255) + padded imgT (256..399) + weight prep (400..867) + L3 warm (868..883) ----------------
__global__ __launch_bounds__(256) void k_pre(const float* __restrict__ task_f,
                      const float* __restrict__ w1A, const float* __restrict__ w1B,
                      float* __restrict__ totA, float* __restrict__ a0A, float* __restrict__ aLA,
                      float* __restrict__ totB, float* __restrict__ a0B, float* __restrict__ aLB,
                      float* __restrict__ rmsacc,
                      const float* __restrict__ img,
                      const float* __restrict__ w1, const float* __restrict__ w2,
                      const float* __restrict__ wa,
                      unsigned short* __restrict__ imgTP,
                      unsigned short* __restrict__ W1T, unsigned short* __restrict__ W2T,
                      unsigned short* __restrict__ WAT,
                      const float* __restrict__ mw1, const float* __restrict__ mw3,
                      const float* __restrict__ bvw1p, const float* __restrict__ bvw2p,
                      const float* __restrict__ bvt2p, const float* __restrict__ atw2p,
                      const float* __restrict__ bankp, float* __restrict__ warm){
  if(blockIdx.x<256){
    int b=blockIdx.x>>6, seg=blockIdx.x&63;
    const float* x=task_f+b*LLEN;
    float tA[4]={0,0,0,0};
    float tB[64];
#pragma unroll
    for(int c=0;c<64;c++) tB[c]=0.f;
    float sq=0.f;
    int l=seg*256+threadIdx.x;
    {
      float xm=(l>0)?x[l-1]:0.f;
      float xc=x[l];
      float xp=(l<LLEN-1)?x[l+1]:0.f;
      sq=xc*xc;
#pragma unroll
      for(int c=0;c<4;c++){
        float a=leaky(w1A[c*3+0]*xm + w1A[c*3+1]*xc + w1A[c*3+2]*xp);
        tA[c]=a;
        if(l==0) a0A[b*4+c]=a;
        if(l==LLEN-1) aLA[b*4+c]=a;
      }
#pragma unroll
      for(int c=0;c<64;c++){
        float a=leaky(w1B[c*3+0]*xm + w1B[c*3+1]*xc + w1B[c*3+2]*xp);
        tB[c]=a;
        if(l==0) a0B[b*64+c]=a;
        if(l==LLEN-1) aLB[b*64+c]=a;
      }
    }
    sq=wave_sum64(sq);
#pragma unroll
    for(int c=0;c<4;c++) tA[c]=wave_sum64(tA[c]);
#pragma unroll
    for(int c=0;c<64;c++){
      float v=tB[c];
      for(int off=32;off;off>>=1) v+=__shfl_down(v,off);
      tB[c]=v;
    }
    __shared__ float redB[4][64];
    __shared__ float redA[4][4];
    __shared__ float redQ[4];
    int wave=threadIdx.x>>6, lane=threadIdx.x&63;
    if(lane==0){
#pragma unroll
      for(int c=0;c<64;c++) redB[wave][c]=tB[c];
#pragma unroll
      for(int c=0;c<4;c++) redA[wave][c]=tA[c];
      redQ[wave]=sq;
    }
    __syncthreads();
    if(threadIdx.x<64){
      float s=redB[0][threadIdx.x]+redB[1][threadIdx.x]+redB[2][threadIdx.x]+redB[3][threadIdx.x];
      atomicAdd(&totB[b*64+threadIdx.x], s);
    } else if(threadIdx.x<68){
      int c=threadIdx.x-64;
      float s=redA[0][c]+redA[1][c]+redA[2][c]+redA[3][c];
      atomicAdd(&totA[b*4+c], s);
    } else if(threadIdx.x==68){
      atomicAdd(&rmsacc[b], redQ[0]+redQ[1]+redQ[2]+redQ[3]);
    }
  } else if(blockIdx.x<400){
    int blk=blockIdx.x-256;
    int b=blk/36, t=blk%36;
    int p0=t*64;
    __shared__ float tile[64][65];
    int pp=threadIdx.x&63, c4=threadIdx.x>>6;
    for(int r=0;r<16;r++){
      int c=c4*16+r;
      tile[c][pp]=img[(b*64+c)*HW + p0+pp];
    }
    __syncthreads();
    int pxl=threadIdx.x>>2, cg=(threadIdx.x&3)*16;
    unsigned out[8];
#pragma unroll
    for(int q=0;q<8;q++){
      unsigned lo=f2bf(tile[cg+2*q][pxl]);
      unsigned hi=f2bf(tile[cg+2*q+1][pxl]);
      out[q]=lo|(hi<<16);
    }
    int px=p0+pxl;
    int h=px/48, w=px-h*48;
    int poff=(h+3)*PP+(w+3);
    unsigned* dst=(unsigned*)(imgTP + ((size_t)(b*PHW+poff))*64 + cg);
#pragma unroll
    for(int q=0;q<8;q++) dst[q]=out[q];
  } else if(blockIdx.x<868){
    int n=(blockIdx.x-400)*256+threadIdx.x;
    if(n<9*64*64){
      int tap=n>>12, oc=(n>>6)&63, c=n&63;
      W1T[n]=f2bf(w1[oc*576+c*9+tap]);
    } else if(n<9*64*64+9*128*64){
      int m=n-9*64*64;
      int tap=m/8192, r=m-tap*8192, oc=r>>6, c=r&63;
      W2T[m]=f2bf(w2[oc*576+c*9+tap]);
    } else {
      int q=n-9*64*64-9*128*64;
      if(q<9*16*64){
        int tap=q>>10, r=q&1023, o=r>>6, c=r&63;
        WAT[q]=(o<8)?f2bf(wa[o*576+c*9+tap]):(unsigned short)0;
      }
    }
  } else {
    int t=(blockIdx.x-868)*256+threadIdx.x;
    float a=0.f;
    for(int i=t;i*16<16384;i+=4096) a+=mw1[i*16];
    for(int i=t;i*16<16384;i+=4096) a+=mw3[i*16];
    for(int i=t;i*16<16384;i+=4096) a+=bvw1p[i*16];
    for(int i=t;i*16<16384;i+=4096) a+=bvw2p[i*16];
    for(int i=t;i*16<24576;i+=4096) a+=bvt2p[i*16];
    for(int i=t;i*16<8192;i+=4096) a+=atw2p[i*16];
    for(int i=t;i*16<16384;i+=4096) a+=bankp[i*16];
    warm[t&1023]=a;
  }
}

// ---------------- k_conv1: ic1 MFMA w/ LDS slab (0..95) + iA MFMA mean (96..119) ----------------
__global__ __launch_bounds__(256) void k_conv1(const unsigned short* __restrict__ imgTP,
                        const unsigned short* __restrict__ W1T,
                        const unsigned short* __restrict__ WAT,
                        const float* __restrict__ bn1, const float* __restrict__ bnA,
                        unsigned short* __restrict__ ie1TP, float* __restrict__ i1){
  int lane=threadIdx.x&63, mt=threadIdx.x>>6;
  int n0=lane&15, kg=lane>>4;
  if(blockIdx.x<96){
    int blk=blockIdx.x;
    int b=blk/24, hp=blk-b*24;
    int h0=hp*2;
    __shared__ unsigned short slab[4*54*SLABP];  // padded rows h0+2..h0+5
    {
      const unsigned short* ibase=imgTP+((size_t)b*PHW+(size_t)(h0+2)*PP)*64;
      for(int e=threadIdx.x;e<4*54*8;e+=256){
        int rr=e/(54*8), rem=e-rr*54*8, w=rem>>3, ck=rem&7;
        uint4 v=*(const uint4*)(ibase+((size_t)(rr*PP+w))*64+ck*8);
        *(uint4*)(slab+(rr*54+w)*SLABP+ck*8)=v;
      }
    }
    __syncthreads();
    floatx4 acc[6];
#pragma unroll
    for(int i=0;i<6;i++) acc[i]=(floatx4){0.f,0.f,0.f,0.f};
#pragma unroll
    for(int ti=0;ti<3;ti++){
#pragma unroll
      for(int tj=0;tj<3;tj++){
        int tap=ti*3+tj;
        const unsigned short* Ab=W1T+(size_t)tap*4096;
#pragma unroll
        for(int c0=0;c0<64;c0+=32){
          short8 a=*(const short8*)(Ab+((mt*16+n0)*64+c0+kg*8));
#pragma unroll
          for(int rr=0;rr<2;rr++){
            int sr=rr+ti;
#pragma unroll
            for(int wc=0;wc<3;wc++){
              int wp=wc*16+n0+tj+2;
              short8 bv=*(const short8*)(slab+(sr*54+wp)*SLABP+c0+kg*8);
              acc[rr*3+wc]=__builtin_amdgcn_mfma_f32_16x16x32_bf16(a,bv,acc[rr*3+wc],0,0,0);
            }
          }
        }
      }
    }
    int obase=mt*16+kg*4;
    float scale[4],m_[4],be_[4];
#pragma unroll
    for(int reg=0;reg<4;reg++){
      int o=obase+reg;
      scale[reg]=bn1[o]/sqrtf(bn1[192+o]+1e-5f);
      m_[reg]=bn1[128+o]; be_[reg]=bn1[64+o];
    }
#pragma unroll
    for(int rr=0;rr<2;rr++){
#pragma unroll
      for(int wc=0;wc<3;wc++){
        int poff=(h0+rr+3)*PP + wc*16+n0+3;
        float v0=leaky((acc[rr*3+wc][0]-m_[0])*scale[0]+be_[0]);
        float v1=leaky((acc[rr*3+wc][1]-m_[1])*scale[1]+be_[1]);
        float v2=leaky((acc[rr*3+wc][2]-m_[2])*scale[2]+be_[2]);
        float v3=leaky((acc[rr*3+wc][3]-m_[3])*scale[3]+be_[3]);
        unsigned w0=f2bf(v0)|((unsigned)f2bf(v1)<<16);
        unsigned w1=f2bf(v2)|((unsigned)f2bf(v3)<<16);
        uint2 pk={w0,w1};
        *(uint2*)(ie1TP+((size_t)(b*PHW+poff)*64+obase))=pk;
      }
    }
  } else {
    int blk=blockIdx.x-96;
    int b=blk/6, hg=blk%6;
    int hp=hg*4+mt;
    int h0=hp*2;
    const unsigned short* ib=imgTP+(size_t)b*PHW*64;
    floatx4 acc[6];
#pragma unroll
    for(int i=0;i<6;i++) acc[i]=(floatx4){0.f,0.f,0.f,0.f};
#pragma unroll
    for(int ti=0;ti<3;ti++){
#pragma unroll
      for(int tj=0;tj<3;tj++){
        int tap=ti*3+tj;
        const unsigned short* Ab=WAT+(size_t)tap*1024;
#pragma unroll
        for(int c0=0;c0<64;c0+=32){
          short8 a=*(const short8*)(Ab+(n0*64+c0+kg*8));
#pragma unroll
          for(int rr=0;rr<2;rr++){
            int r=h0+rr+ti-1+3;
#pragma unroll
            for(int wc=0;wc<3;wc++){
              int w=wc*16+n0+tj-1+3;
              short8 bv=*(const short8*)(ib+((size_t)(r*PP+w)*64+c0+kg*8));
              acc[rr*3+wc]=__builtin_amdgcn_mfma_f32_16x16x32_bf16(a,bv,acc[rr*3+wc],0,0,0);
            }
          }
        }
      }
    }
    int obase=kg*4;
#pragma unroll
    for(int reg=0;reg<4;reg++){
      int o=obase+reg;
      float part=0;
      if(o<8){
        float scale=bnA[o]/sqrtf(bnA[24+o]+1e-5f);
        float m_=bnA[16+o], be_=bnA[8+o];
#pragma unroll
        for(int i=0;i<6;i++) part+=leaky((acc[i][reg]-m_)*scale+be_);
      }
      for(int off=1;off<16;off<<=1) part+=__shfl_xor(part,off);
      if(n0==0 && o<8) atomicAdd(&i1[b*8+o], part*(1.f/2304.f));
    }
  }
}

// ---------------- bv_ic2 conv via MFMA + mean; 512 threads, M=128 in-block, LDS slab ----------------
__global__ __launch_bounds__(512) void k_ic2M(const unsigned short* __restrict__ ie1TP,
                       const unsigned short* __restrict__ W2T,
                       const float* __restrict__ bn, float* __restrict__ ie){
  int blk=blockIdx.x;
  int b=blk/24, hp=blk-b*24;
  int tid=threadIdx.x;
  int lane=tid&63, mt=tid>>6;        // 8 waves -> M-tiles 0..7 (oc 0..127)
  int n0=lane&15, kg=lane>>4;
  int h0=hp*2;
  __shared__ unsigned short slab[4*54*SLABP];  // padded rows h0+2..h0+5
  {
    const unsigned short* ibase=ie1TP+((size_t)b*PHW+(size_t)(h0+2)*PP)*64;
    for(int e=tid;e<4*54*8;e+=512){
      int rr=e/(54*8), rem=e-rr*54*8, w=rem>>3, ck=rem&7;
      uint4 v=*(const uint4*)(ibase+((size_t)(rr*PP+w))*64+ck*8);
      *(uint4*)(slab+(rr*54+w)*SLABP+ck*8)=v;
    }
  }
  __syncthreads();
  floatx4 acc[6];
#pragma unroll
  for(int i=0;i<6;i++) acc[i]=(floatx4){0.f,0.f,0.f,0.f};
#pragma unroll
  for(int ti=0;ti<3;ti++){
#pragma unroll
    for(int tj=0;tj<3;tj++){
      int tap=ti*3+tj;
      const unsigned short* Ab=W2T+(size_t)tap*8192;
#pragma unroll
      for(int c0=0;c0<64;c0+=32){
        short8 a=*(const short8*)(Ab+((mt*16+n0)*64+c0+kg*8));
#pragma unroll
        for(int rr=0;rr<2;rr++){
          int sr=rr+ti;
#pragma unroll
          for(int wc=0;wc<3;wc++){
            int wp=wc*16+n0+tj+2;
            short8 bv=*(const short8*)(slab+(sr*54+wp)*SLABP+c0+kg*8);
            acc[rr*3+wc]=__builtin_amdgcn_mfma_f32_16x16x32_bf16(a,bv,acc[rr*3+wc],0,0,0);
          }
        }
      }
    }
  }
  int obase=mt*16+kg*4;
#pragma unroll
  for(int reg=0;reg<4;reg++){
    int o=obase+reg;
    float scale=bn[o]/sqrtf(bn[384+o]+1e-5f);
    float m_=bn[256+o], be_=bn[128+o];
    float part=0;
#pragma unroll
    for(int i=0;i<6;i++) part+=leaky((acc[i][reg]-m_)*scale+be_);
    for(int off=1;off<16;off<<=1) part+=__shfl_xor(part,off);
    if(n0==0) atomicAdd(&ie[b*128+o], part*(1.f/2304.f));
  }
}

// ---------------- fused mid, PER-BATCH block (grid=4, 512 threads, K-split stages) ----------------
__global__ __launch_bounds__(512,1) void k_mid(
    const float* __restrict__ totA, const float* __restrict__ a0A, const float* __restrict__ aLA,
    const float* __restrict__ totB, const float* __restrict__ a0B, const float* __restrict__ aLB,
    const float* __restrict__ rmsacc,
    const float* __restrict__ tA_w2, const float* __restrict__ bv_t2,
    const float* __restrict__ i1, const float* __restrict__ ie,
    const float* __restrict__ at_w1, const float* __restrict__ at_b1,
    const float* __restrict__ at_ln_g, const float* __restrict__ at_ln_b,
    const float* __restrict__ at_w2, const float* __restrict__ at_b2,
    const float* __restrict__ protos,
    const float* __restrict__ bv_w1, const float* __restrict__ bv_b1,
    const float* __restrict__ bv_ln_g, const float* __restrict__ bv_ln_b,
    const float* __restrict__ bv_w2, const float* __restrict__ bv_b2,
    const float* __restrict__ bank,
    const float* __restrict__ m1_w1, const float* __restrict__ m1_b1,
    const float* __restrict__ m1_g,  const float* __restrict__ m1_bb,
    const float* __restrict__ m3_w1, const float* __restrict__ m3_b1,
    const float* __restrict__ m3_g,  const float* __restrict__ m3_bb,
    int* __restrict__ idxo, float* __restrict__ hid1, float* __restrict__ hid3){
  int b=blockIdx.x;
  int tid=threadIdx.x;
  int lane=tid&63, wv=tid>>6;
  const float invL=1.0f/16384.0f;
  __shared__ float sT[64], s0[64], sL[64];
  __shared__ float part[512];
  __shared__ float te_s[128], t1_s[8];
  __shared__ float f1[16], h[64], tif[128], tifn[128], tden[8], pden[4], pn[64], z[32];
  __shared__ int sidx[8], sfirst[4], srank[8], rows[8];
  __shared__ float fbuf[256], hh[64], ffn_s[256], finv_s;
  __shared__ float scores[64];
  __shared__ int order[64];
  __shared__ float bvf[2048];

  if(tid<64){ sT[tid]=totB[b*64+tid]; s0[tid]=a0B[b*64+tid]; sL[tid]=aLB[b*64+tid]; }
  __syncthreads();
  float scB=1.0f/(sqrtf(rmsacc[b]*invL)+1e-8f);
  if(tid<256){
    int c2=tid&127, h2=tid>>7;
    const float* wr=bv_t2+c2*192;
    float s=0;
    for(int c1=h2*32;c1<h2*32+32;c1+=8){
      float4 q[6];
      const float4* r4=(const float4*)(wr+c1*3);
#pragma unroll
      for(int u=0;u<6;u++) q[u]=r4[u];
      const float* qq=(const float*)q;
#pragma unroll
      for(int u=0;u<8;u++){
        int c=c1+u;
        float T=sT[c], A0=s0[c], AL=sL[c];
        s += qq[u*3+0]*(T-AL) + qq[u*3+1]*T + qq[u*3+2]*(T-A0);
      }
    }
    part[tid]=s;
  } else if(tid>=384 && tid<392){
    int c2=tid-384;
    float s=0;
    for(int c1=0;c1<4;c1++){
      float T=totA[b*4+c1], A0=a0A[b*4+c1], AL=aLA[b*4+c1];
      const float* w=&tA_w2[(c2*4+c1)*3];
      s += w[0]*(T-AL) + w[1]*T + w[2]*(T-A0);
    }
    t1_s[c2]=s*invL;
  }
  __syncthreads();
  if(tid<128) te_s[tid]=(part[tid]+part[tid+128])*invL*scB;
  __syncthreads();

  if(tid<8) f1[tid]=t1_s[tid];
  else if(tid<16) f1[tid]=i1[b*8+tid-8];
  __syncthreads();
  if(tid<64){
    float s=at_b1[lane];
#pragma unroll
    for(int i=0;i<16;i++) s+=f1[i]*at_w1[i*64+lane];
    float mu=wave_sum64(s)*(1.f/64.f);
    float d=s-mu;
    float var=wave_sum64(d*d)*(1.f/64.f);
    h[lane]=fmaxf(d*(1.0f/sqrtf(var+1e-5f))*at_ln_g[lane]+at_ln_b[lane],0.f);
  }
  __syncthreads();
  if(tid<256){
    int n=tid&127, h2=tid>>7;
    float a0=0,a1=0;
    for(int k=h2*32;k<h2*32+32;k+=2){
      a0+=h[k]*at_w2[k*128+n];
      a1+=h[k+1]*at_w2[(k+1)*128+n];
    }
    part[tid]=a0+a1;
  }
  __syncthreads();
  if(tid<128) tif[tid]=at_b2[tid]+part[tid]+part[tid+128];
  __syncthreads();
  if(tid<8){
    int f=tid;
    float ss=0; for(int e=0;e<16;e++){float v=tif[e*8+f]; ss+=v*v;}
    tden[f]=fmaxf(sqrtf(ss),1e-8f);
  } else if(tid<12){
    int t=tid-8;
    float ss=0; for(int e=0;e<16;e++){float v=protos[t*16+e]; ss+=v*v;}
    pden[t]=fmaxf(sqrtf(ss),1e-8f);
  }
  __syncthreads();
  if(tid<128) tifn[tid]=tif[tid]/tden[tid&7];
  if(tid<64) pn[tid]=protos[tid]/pden[tid>>4];
  __syncthreads();
  if(tid<32){
    int f=tid>>2, t=tid&3;
    float ss=0;
#pragma unroll
    for(int e=0;e<16;e++) ss+=pn[t*16+e]*tifn[e*8+f];
    float u=jax_uniform128(b*32+f*4+t);
    float g=-logf(-logf(u));
    z[tid]=ss+g;
  }
  __syncthreads();
  if(tid<8){
    float best=z[tid*4]; int bi=0;
    for(int t=1;t<4;t++){ float v=z[tid*4+t]; if(v>best){best=v;bi=t;} }
    sidx[tid]=bi;
  }
  __syncthreads();
  if(tid<4){
    int t=tid;
    int fi=0;
    for(int f=7;f>=0;f--) if(sidx[f]==t) fi=f;
    sfirst[t]=fi;
  } else if(tid<12){
    int f=tid-4;
    int c=0; for(int f2=0;f2<f;f2++) if(sidx[f2]==sidx[f]) c++;
    srank[f]=c;
  }
  __syncthreads();

  if(tid<128) fbuf[tid]=te_s[tid];
  else if(tid<256) fbuf[tid]=ie[b*128+tid-128];
  __syncthreads();
  if(tid<256){
    int l64=tid&63, q=tid>>6;
    float a0=0,a1=0,a2=0,a3=0;
    for(int k=q*64;k<q*64+64;k+=4){
      a0+=fbuf[k]  *bv_w1[k*64+l64];
      a1+=fbuf[k+1]*bv_w1[(k+1)*64+l64];
      a2+=fbuf[k+2]*bv_w1[(k+2)*64+l64];
      a3+=fbuf[k+3]*bv_w1[(k+3)*64+l64];
    }
    part[tid]=((a0+a1)+(a2+a3));
  }
  __syncthreads();
  if(tid<64){
    float s=bv_b1[lane]+part[lane]+part[64+lane]+part[128+lane]+part[192+lane];
    float mu=wave_sum64(s)*(1.f/64.f);
    float d=s-mu;
    float var=wave_sum64(d*d)*(1.f/64.f);
    hh[lane]=fmaxf(d*(1.0f/sqrtf(var+1e-5f))*bv_ln_g[lane]+bv_ln_b[lane],0.f);
  }
  __syncthreads();
  {
    int n=tid&255, h2=tid>>8;
    float a0=0,a1=0;
    for(int k=h2*32;k<h2*32+32;k+=2){
      a0+=hh[k]*bv_w2[k*256+n];
      a1+=hh[k+1]*bv_w2[(k+1)*256+n];
    }
    part[tid]=a0+a1;
  }
  __syncthreads();
  if(tid<256) ffn_s[tid]=bv_b2[tid]+part[tid]+part[tid+256];
  __syncthreads();
  if(tid<64){
    float sq=0;
#pragma unroll
    for(int u=0;u<4;u++){ float v=ffn_s[u*64+lane]; sq+=v*v; }
    sq=wave_sum64(sq);
    if(lane==0) finv_s=1.0f/fmaxf(sqrtf(sq),1e-12f);
  }
  __syncthreads();
  if(tid<256) ffn_s[tid]*=finv_s;
  __syncthreads();

  if(tid<128){
    int it=tid&63, h2=tid>>6;
    int t=it>>4, v=it&15;
    int tt=sidx[sfirst[t]];
    const float4* row=(const float4*)(bank+(tt*16+v)*256);
    float sa=0,na=0;
    for(int d4=h2*32;d4<h2*32+32;d4++){
      float4 r=row[d4];
      const float* fp=&ffn_s[d4*4];
      sa+=fp[0]*r.x+fp[1]*r.y+fp[2]*r.z+fp[3]*r.w;
      na+=r.x*r.x+r.y*r.y+r.z*r.z+r.w*r.w;
    }
    part[tid]=sa;
    part[256+tid]=na;
  }
  __syncthreads();
  if(tid<64) scores[tid]=(part[tid]+part[tid+64])/fmaxf(sqrtf(part[256+tid]+part[320+tid]),1e-12f);
  __syncthreads();
  if(tid<4){
    const float* sc=&scores[tid*16];
    unsigned used=0;
    for(int pk=0;pk<16;pk++){
      int best=-1; float bv=-1e30f;
      for(int v2=0;v2<16;v2++){
        if(used&(1u<<v2)) continue;
        float vv=sc[v2];
        if(best<0||vv>bv){bv=vv;best=v2;}
      }
      used|=1u<<best;
      order[tid*16+pk]=best;
    }
  }
  __syncthreads();
  if(tid<8){
    int t=sidx[tid];
    int v=order[t*16+srank[tid]];
    rows[tid]=t*16+v;
    idxo[b*8+tid]=t;
  }
  __syncthreads();

  for(int ii=tid;ii<2048;ii+=512){
    int r=ii>>8, d=ii&255;
    bvf[ii]=bank[rows[r]*256+d];
  }
  __syncthreads();
  {
    int r=wv;
    const float* bp=&bvf[r*256];
    float a0=0,a1=0,a2=0,a3=0;
    float c0=0,c1=0,c2=0,c3=0;
    for(int d=0;d<256;d+=4){
      float b0=bp[d],b1=bp[d+1],b2=bp[d+2],b3=bp[d+3];
      a0+=b0*m1_w1[d*64+lane];
      a1+=b1*m1_w1[(d+1)*64+lane];
      a2+=b2*m1_w1[(d+2)*64+lane];
      a3+=b3*m1_w1[(d+3)*64+lane];
      c0+=b0*m3_w1[d*64+lane];
      c1+=b1*m3_w1[(d+1)*64+lane];
      c2+=b2*m3_w1[(d+2)*64+lane];
      c3+=b3*m3_w1[(d+3)*64+lane];
    }
    float s1=m1_b1[lane]+((a0+a1)+(a2+a3));
    float s3=m3_b1[lane]+((c0+c1)+(c2+c3));
    float mu=wave_sum64(s1)*(1.f/64.f);
    float dd=s1-mu;
    float var=wave_sum64(dd*dd)*(1.f/64.f);
    hid1[(b*8+r)*64+lane]=fmaxf(dd*(1.0f/sqrtf(var+1e-5f))*m1_g[lane]+m1_bb[lane],0.f);
    mu=wave_sum64(s3)*(1.f/64.f);
    dd=s3-mu;
    var=wave_sum64(dd*dd)*(1.f/64.f);
    hid3[(b*8+r)*64+lane]=fmaxf(dd*(1.0f/sqrtf(var+1e-5f))*m3_g[lane]+m3_bb[lane],0.f);
  }
}

// ---------------- k_heads ----------------
__global__ __launch_bounds__(256) void k_heads(const float* __restrict__ hid1, const float* __restrict__ hid3,
                        const float* __restrict__ w2a, const float* __restrict__ b2a,
                        const float* __restrict__ w2b, const float* __restrict__ b2b,
                        unsigned short* __restrict__ A1, unsigned short* __restrict__ A3){
  __shared__ float hl[2048];
  if(blockIdx.x<16){
    int n=blockIdx.x*256+threadIdx.x;
    for(int i=threadIdx.x;i<2048;i+=256) hl[i]=hid1[i];
    __syncthreads();
    float wcol[64];
#pragma unroll
    for(int k=0;k<64;k++) wcol[k]=w2a[k*4096+n];
    float bb=b2a[n];
    for(int bf=0;bf<32;bf++){
      float s=bb;
#pragma unroll
      for(int k=0;k<64;k++) s+=hl[bf*64+k]*wcol[k];
      A1[bf*4096+n]=f2bf(s);
    }
  } else {
    int n=(blockIdx.x-16)*256+threadIdx.x;
    for(int i=threadIdx.x;i<2048;i+=256) hl[i]=hid3[i];
    __syncthreads();
    float wcol[64];
#pragma unroll
    for(int k=0;k<64;k++) wcol[k]=w2b[(size_t)k*36864+n];
    float bb=b2b[n];
    int o=n/576, rem=n-o*576;
    int c=rem/9, tap=rem-c*9;
    size_t base=((size_t)tap*64+o)*64+c;
    for(int bf=0;bf<32;bf++){
      float s=bb;
#pragma unroll
      for(int k=0;k<64;k++) s+=hl[bf*64+k]*wcol[k];
      A3[(size_t)bf*9*4096+base]=f2bf(s);
    }
  }
}

// ---------------- fused dynamic conv: LDS-staged image slab, 512 thr, f-halves, zc+residual ----------------
__global__ __launch_bounds__(512) void k_dynF(const unsigned short* __restrict__ imgTP,
                       const unsigned short* __restrict__ A1, const unsigned short* __restrict__ A3,
                       const int* __restrict__ idx, const float* __restrict__ bn,
                       const float* __restrict__ zc_w, const float* __restrict__ zc_b,
                       const float* __restrict__ img, float* __restrict__ out){
  int blk=blockIdx.x;
  int b=blk/48, r0=blk-b*48;
  int tid=threadIdx.x;
  int lane=tid&63, w8=tid>>6;
  int mt=w8&3, fh=w8>>2;
  int n0=lane&15, kg=lane>>4;
  __shared__ unsigned short slab[7*54*SLABP];
  __shared__ float xl[64*50];
  __shared__ float zl[4096];
  for(int i=tid;i<4096;i+=512) zl[i]=zc_w[i];
  for(int i=tid;i<3200;i+=512) xl[i]=0.f;
  {
    const unsigned short* ibase=imgTP+((size_t)b*PHW+(size_t)r0*PP)*64;
    for(int e=tid;e<7*54*8;e+=512){
      int rr=e/(54*8), rem=e-rr*54*8, w=rem>>3, ck=rem&7;
      uint4 v=*(const uint4*)(ibase + ((size_t)(rr*PP+w))*64 + ck*8);
      *(uint4*)(slab + (rr*54+w)*SLABP + ck*8)=v;
    }
  }
  __syncthreads();
  int obase=mt*16+kg*4;
  float scale[4],m_[4],be_[4];
#pragma unroll
  for(int reg=0;reg<4;reg++){
    int o=obase+reg;
    scale[reg]=bn[o]/sqrtf(bn[192+o]+1e-5f);
    m_[reg]=bn[128+o]; be_[reg]=bn[64+o];
  }
  float xsum[3][4];
#pragma unroll
  for(int wc=0;wc<3;wc++)
#pragma unroll
    for(int reg=0;reg<4;reg++) xsum[wc][reg]=0.f;
  for(int f=fh*4;f<fh*4+4;f++){
    int bf=b*8+f;
    int tt=idx[bf];
    floatx4 acc[3];
#pragma unroll
    for(int i=0;i<3;i++) acc[i]=(floatx4){0.f,0.f,0.f,0.f};
    if(tt==0){
      const unsigned short* Ab=A1+(size_t)bf*4096;
#pragma unroll
      for(int c0=0;c0<64;c0+=32){
        short8 a=*(const short8*)(Ab+((mt*16+n0)*64+c0+kg*8));
#pragma unroll
        for(int wc=0;wc<3;wc++){
          short8 bv=*(const short8*)(slab + (3*54 + wc*16+n0+3)*SLABP + c0+kg*8);
          acc[wc]=__builtin_amdgcn_mfma_f32_16x16x32_bf16(a,bv,acc[wc],0,0,0);
        }
      }
    } else {
      int d=tt;
      const unsigned short* A3b=A3+(size_t)bf*9*4096;
#pragma unroll
      for(int ti=0;ti<3;ti++){
        int lr=d*(ti-1)+3;
#pragma unroll
        for(int tj=0;tj<3;tj++){
          int tap=ti*3+tj;
          int dw=d*(tj-1)+3;
          const unsigned short* Ab=A3b+(size_t)tap*4096;
#pragma unroll
          for(int c0=0;c0<64;c0+=32){
            short8 a=*(const short8*)(Ab+((mt*16+n0)*64+c0+kg*8));
#pragma unroll
            for(int wc=0;wc<3;wc++){
              short8 bv=*(const short8*)(slab + (lr*54 + wc*16+n0+dw)*SLABP + c0+kg*8);
              acc[wc]=__builtin_amdgcn_mfma_f32_16x16x32_bf16(a,bv,acc[wc],0,0,0);
            }
          }
        }
      }
    }
#pragma unroll
    for(int wc=0;wc<3;wc++)
#pragma unroll
      for(int reg=0;reg<4;reg++)
        xsum[wc][reg]+=leaky((acc[wc][reg]-m_[reg])*scale[reg]+be_[reg]);
  }
#pragma unroll
  for(int wc=0;wc<3;wc++)
#pragma unroll
    for(int reg=0;reg<4;reg++)
      atomicAdd(&xl[(obase+reg)*50 + wc*16+n0], xsum[wc][reg]*0.125f);
  __syncthreads();
  size_t base=(size_t)b*64*HW + r0*48;
  for(int e=tid;e<3072;e+=512){
    int o=e/48, px=e-o*48;
    float s=zc_b[o];
#pragma unroll
    for(int c=0;c<64;c++) s+=zl[o*64+c]*xl[c*50+px];
    size_t a=base+(size_t)o*HW+px;
    out[a]=s+img[a];
  }
}

extern "C" void kernel_launch(void* const* d_in, const int* in_sizes, int n_in,
                              void* d_out, int out_size, void* d_ws, size_t ws_size,
                              hipStream_t stream){
  const float* bank   =(const float*)d_in[0];
  const float* task_f =(const float*)d_in[1];
  const float* img_f  =(const float*)d_in[2];
  const float* protos =(const float*)d_in[3];
  const float* tA_w1  =(const float*)d_in[4];
  const float* tA_w2  =(const float*)d_in[5];
  const float* iA_w   =(const float*)d_in[6];
  const float* iA_bn  =(const float*)d_in[7];
  const float* at_w1  =(const float*)d_in[8];
  const float* at_b1  =(const float*)d_in[9];
  const float* at_ln_g=(const float*)d_in[10];
  const float* at_ln_b=(const float*)d_in[11];
  const float* at_w2  =(const float*)d_in[12];
  const float* at_b2  =(const float*)d_in[13];
  const float* bv_t1  =(const float*)d_in[14];
  const float* bv_t2  =(const float*)d_in[15];
  const float* bv_ic1 =(const float*)d_in[16];
  const float* bv_bn1 =(const float*)d_in[17];
  const float* bv_ic2 =(const float*)d_in[18];
  const float* bv_bn2 =(const float*)d_in[19];
  const float* bv_w1  =(const float*)d_in[20];
  const float* bv_b1  =(const float*)d_in[21];
  const float* bv_ln_g=(const float*)d_in[22];
  const float* bv_ln_b=(const float*)d_in[23];
  const float* bv_w2  =(const float*)d_in[24];
  const float* bv_b2  =(const float*)d_in[25];
  const float* m1_w1  =(const float*)d_in[26];
  const float* m1_b1  =(const float*)d_in[27];
  const float* m1_ln_g=(const float*)d_in[28];
  const float* m1_ln_b=(const float*)d_in[29];
  const float* m1_w2  =(const float*)d_in[30];
  const float* m1_b2  =(const float*)d_in[31];
  const float* m3_w1  =(const float*)d_in[32];
  const float* m3_b1  =(const float*)d_in[33];
  const float* m3_ln_g=(const float*)d_in[34];
  const float* m3_ln_b=(const float*)d_in[35];
  const float* m3_w2  =(const float*)d_in[36];
  const float* m3_b2  =(const float*)d_in[37];
  const float* blr_bn =(const float*)d_in[38];
  const float* zc_w   =(const float*)d_in[39];
  const float* zc_b   =(const float*)d_in[40];

  float* ws=(float*)d_ws;
  float* totA=ws+0;       float* a0A=ws+16;      float* aLA=ws+32;
  float* totB=ws+48;      float* a0B=ws+304;     float* aLB=ws+560;
  float* rmsacc=ws+816;   float* i1 =ws+820;     float* ie =ws+852;   // ..1364
  int*   idxp  =(int*)(ws+2932);
  float* hid1=ws+3044;    float* hid3=ws+5092;
  unsigned short* A1p  =(unsigned short*)(ws+7140);     // 131072 bf16
  unsigned short* A3p  =(unsigned short*)(ws+72676);    // 1179648 bf16
  unsigned short* imgTP=(unsigned short*)(ws+662500);   // 746496 bf16 (padded)
  unsigned short* ie1TP=(unsigned short*)(ws+1035748);  // 746496 bf16 (padded)
  unsigned short* W1Tp =(unsigned short*)(ws+1408996);  // 36864 bf16
  unsigned short* W2Tp =(unsigned short*)(ws+1427428);  // 73728 bf16
  unsigned short* WATp =(unsigned short*)(ws+1464292);  // 9216 bf16 -> ends 1468900
  float* warm =ws+1468900;                              // 1024 f dummy sink
  // total ~5.9 MB

  hipMemsetAsync(ws, 0, 1364*sizeof(float), stream);                 // stats accumulators
  hipMemsetAsync(imgTP, 0, 2*746496*sizeof(unsigned short), stream); // padded halos

  k_pre<<<884,256,0,stream>>>(task_f, tA_w1, bv_t1,
                              totA, a0A, aLA, totB, a0B, aLB, rmsacc,
                              img_f, bv_ic1, bv_ic2, iA_w, imgTP, W1Tp, W2Tp, WATp,
                              m1_w1, m3_w1, bv_w1, bv_w2, bv_t2, at_w2, bank, warm);
  k_conv1<<<120,256,0,stream>>>(imgTP, W1Tp, WATp, bv_bn1, iA_bn, ie1TP, i1);
  k_ic2M<<<96,512,0,stream>>>(ie1TP, W2Tp, bv_bn2, ie);
  k_mid<<<4,512,0,stream>>>(totA,a0A,aLA,totB,a0B,aLB, rmsacc, tA_w2, bv_t2, i1, ie,
                            at_w1, at_b1, at_ln_g, at_ln_b, at_w2, at_b2, protos,
                            bv_w1, bv_b1, bv_ln_g, bv_ln_b, bv_w2, bv_b2, bank,
                            m1_w1, m1_b1, m1_ln_g, m1_ln_b,
                            m3_w1, m3_b1, m3_ln_g, m3_ln_b,
                            idxp, hid1, hid3);
  k_heads<<<160,256,0,stream>>>(hid1, hid3, m1_w2, m1_b2, m3_w2, m3_b2, A1p, A3p);
  k_dynF<<<192,512,0,stream>>>(imgTP, A1p, A3p, idxp, blr_bn, zc_w, zc_b, img_f, (float*)d_out);

  (void)in_sizes; (void)n_in; (void)out_size; (void)ws_size;
}